// Round 1
// baseline (1164.790 us; speedup 1.0000x reference)
//
#include <hip/hip_runtime.h>
#include <math.h>

namespace {

constexpr int NB = 4, NS = 2048, ND = 256, NH = 4, NDK = 64, NL = 2, NT = 1000;

// ---------------- embedding gather: h = event_emb[x] + time_emb[clip(td)] ----
__global__ __launch_bounds__(256) void k_embed(const int* __restrict__ x,
                                               const int* __restrict__ td,
                                               const float* __restrict__ ee,
                                               const float* __restrict__ te,
                                               float* __restrict__ h) {
  int row = blockIdx.x;       // 0 .. NB*NS-1
  int d = threadIdx.x;        // 0 .. 255
  int xi = x[row];
  int tb = td[row];
  tb = tb < 0 ? 0 : (tb >= NT ? NT - 1 : tb);
  h[row * ND + d] = ee[xi * ND + d] + te[tb * ND + d];
}

// ---------------- fused QKV projection: 16-row tile per block ----------------
__global__ __launch_bounds__(256) void k_qkv(const float* __restrict__ h,
                                             const float* __restrict__ Wq, const float* __restrict__ bq,
                                             const float* __restrict__ Wk, const float* __restrict__ bk,
                                             const float* __restrict__ Wv, const float* __restrict__ bv,
                                             float* __restrict__ q, float* __restrict__ k,
                                             float* __restrict__ v) {
  __shared__ float tile[16][ND];
  int col = threadIdx.x;
  int row0 = blockIdx.x * 16;
  #pragma unroll
  for (int r = 0; r < 16; ++r) tile[r][col] = h[(row0 + r) * ND + col];
  __syncthreads();
  float aq[16], ak[16], av[16];
  #pragma unroll
  for (int r = 0; r < 16; ++r) { aq[r] = 0.f; ak[r] = 0.f; av[r] = 0.f; }
  for (int kk = 0; kk < ND; ++kk) {
    float wq = Wq[kk * ND + col];
    float wk = Wk[kk * ND + col];
    float wv = Wv[kk * ND + col];
    #pragma unroll
    for (int r = 0; r < 16; ++r) {
      float hv = tile[r][kk];
      aq[r] = fmaf(hv, wq, aq[r]);
      ak[r] = fmaf(hv, wk, ak[r]);
      av[r] = fmaf(hv, wv, av[r]);
    }
  }
  float bbq = bq[col], bbk = bk[col], bbv = bv[col];
  #pragma unroll
  for (int r = 0; r < 16; ++r) {
    q[(row0 + r) * ND + col] = aq[r] + bbq;
    k[(row0 + r) * ND + col] = ak[r] + bbk;
    v[(row0 + r) * ND + col] = av[r] + bbv;
  }
}

// ---------------- flash attention: 16 queries x 64-key blocks ----------------
// thread t: ql = t>>4 (query within tile), quad = t&15 (dim group / key group)
__global__ __launch_bounds__(256) void k_attn(const float* __restrict__ q,
                                              const float* __restrict__ k,
                                              const float* __restrict__ v,
                                              const int* __restrict__ td,
                                              const int* __restrict__ mask,
                                              const float* __restrict__ tp,
                                              float* __restrict__ ctx, int q_base) {
  constexpr int QT = 16, KT = 64, PAD = 68;
  __shared__ float kt[KT][PAD];
  __shared__ float vt[KT][PAD];
  __shared__ float st[QT][KT];
  __shared__ float sbias[KT];
  __shared__ int smask[KT];

  int tid = threadIdx.x;
  int b = blockIdx.z, hh = blockIdx.y;
  int q0 = q_base + blockIdx.x * QT;
  int ql = tid >> 4;
  int quad = tid & 15;
  int d0 = quad * 4;

  // this thread's full 64-dim query row in registers
  float4 qr[16];
  const float4* qsrc = (const float4*)&q[(b * NS + q0 + ql) * ND + hh * NDK];
  #pragma unroll
  for (int i = 0; i < 16; ++i) qr[i] = qsrc[i];

  float o0 = 0.f, o1 = 0.f, o2 = 0.f, o3 = 0.f;
  float m = -1e30f, lsum = 0.f;

  for (int kb = 0; kb < NS / KT; ++kb) {
    int k0 = kb * KT;
    __syncthreads();  // previous tile fully consumed
    for (int i = tid; i < KT * NDK; i += 256) {
      int r = i >> 6, d = i & 63;
      kt[r][d] = k[(b * NS + k0 + r) * ND + hh * NDK + d];
      vt[r][d] = v[(b * NS + k0 + r) * ND + hh * NDK + d];
    }
    if (tid < KT) {
      int key = k0 + tid;
      int tb = td[b * NS + key];
      tb = tb < 0 ? 0 : (tb >= NT ? NT - 1 : tb);
      sbias[tid] = tp[tb * NH + hh];
      smask[tid] = mask[b * NS + key];
    }
    __syncthreads();

    // scores: thread handles keys kk = quad + 16*j (row-bank spread)
    float sc[4];
    #pragma unroll
    for (int j = 0; j < 4; ++j) {
      int kk = quad + 16 * j;
      const float4* krow = (const float4*)&kt[kk][0];
      float s = 0.f;
      #pragma unroll
      for (int d4 = 0; d4 < 16; ++d4) {
        float4 a = qr[d4], bb = krow[d4];
        s = fmaf(a.x, bb.x, s); s = fmaf(a.y, bb.y, s);
        s = fmaf(a.z, bb.z, s); s = fmaf(a.w, bb.w, s);
      }
      s = s * 0.125f + sbias[kk];
      if (smask[kk] == 0) s = -1e9f;
      sc[j] = s;
      st[ql][kk] = s;
    }
    __syncthreads();

    // running max (redundant per 16-thread query group, deterministic)
    float mnew = m;
    #pragma unroll
    for (int kk = 0; kk < KT; ++kk) mnew = fmaxf(mnew, st[ql][kk]);
    float scale = __expf(m - mnew);
    __syncthreads();  // all max reads done before p overwrite

    #pragma unroll
    for (int j = 0; j < 4; ++j) st[ql][quad + 16 * j] = __expf(sc[j] - mnew);
    __syncthreads();

    lsum *= scale; o0 *= scale; o1 *= scale; o2 *= scale; o3 *= scale;
    #pragma unroll
    for (int kk = 0; kk < KT; ++kk) {
      float p = st[ql][kk];
      lsum += p;
      const float4 vv = *(const float4*)&vt[kk][d0];
      o0 = fmaf(p, vv.x, o0); o1 = fmaf(p, vv.y, o1);
      o2 = fmaf(p, vv.z, o2); o3 = fmaf(p, vv.w, o3);
    }
    m = mnew;
  }

  float inv = 1.f / lsum;
  float* od = &ctx[(b * NS + q0 + ql) * ND + hh * NDK + d0];
  od[0] = o0 * inv; od[1] = o1 * inv; od[2] = o2 * inv; od[3] = o3 * inv;
}

// ---------------- output projection: out = in @ W + bias ---------------------
__global__ __launch_bounds__(256) void k_proj(const float* __restrict__ in,
                                              const float* __restrict__ W,
                                              const float* __restrict__ bias,
                                              float* __restrict__ out, int q_base) {
  __shared__ float tile[16][ND];
  int col = threadIdx.x;
  int row0 = blockIdx.y * NS + q_base + blockIdx.x * 16;
  #pragma unroll
  for (int r = 0; r < 16; ++r) tile[r][col] = in[(row0 + r) * ND + col];
  __syncthreads();
  float acc[16];
  #pragma unroll
  for (int r = 0; r < 16; ++r) acc[r] = 0.f;
  for (int kk = 0; kk < ND; ++kk) {
    float w = W[kk * ND + col];
    #pragma unroll
    for (int r = 0; r < 16; ++r) acc[r] = fmaf(tile[r][kk], w, acc[r]);
  }
  float bb = bias[col];
  #pragma unroll
  for (int r = 0; r < 16; ++r) out[(row0 + r) * ND + col] = acc[r] + bb;
}

// ---------------- layernorm over D=256, in place -----------------------------
__global__ __launch_bounds__(256) void k_ln(float* __restrict__ h,
                                            const float* __restrict__ g,
                                            const float* __restrict__ bb, int q_base) {
  __shared__ float red[ND];
  int row = blockIdx.y * NS + q_base + blockIdx.x;
  int d = threadIdx.x;
  float val = h[row * ND + d];
  red[d] = val;
  __syncthreads();
  for (int off = 128; off > 0; off >>= 1) {
    if (d < off) red[d] += red[d + off];
    __syncthreads();
  }
  float mu = red[0] * (1.f / ND);
  __syncthreads();
  float diff = val - mu;
  red[d] = diff * diff;
  __syncthreads();
  for (int off = 128; off > 0; off >>= 1) {
    if (d < off) red[d] += red[d + off];
    __syncthreads();
  }
  float var = red[0] * (1.f / ND);
  float r = rsqrtf(var + 1e-5f);
  h[row * ND + d] = diff * r * g[d] + bb[d];
}

// ---------------- classifier head on last token ------------------------------
__global__ __launch_bounds__(128) void k_head(const float* __restrict__ h,
                                              const float* __restrict__ Wc1,
                                              const float* __restrict__ bc1,
                                              const float* __restrict__ Wc2,
                                              const float* __restrict__ bc2,
                                              float* __restrict__ out) {
  __shared__ float red[128];
  int j = threadIdx.x;  // 0..127
  for (int b = 0; b < NB; ++b) {
    const float* last = &h[(b * NS + NS - 1) * ND];
    float acc = bc1[j];
    for (int d = 0; d < ND; ++d) acc = fmaf(last[d], Wc1[d * 128 + j], acc);
    acc = fmaxf(acc, 0.f);
    red[j] = acc * Wc2[j];
    __syncthreads();
    for (int off = 64; off > 0; off >>= 1) {
      if (j < off) red[j] += red[j + off];
      __syncthreads();
    }
    if (j == 0) out[b] = 1.f / (1.f + __expf(-(red[0] + bc2[0])));
    __syncthreads();
  }
}

}  // namespace

extern "C" void kernel_launch(void* const* d_in, const int* in_sizes, int n_in,
                              void* d_out, int out_size, void* d_ws, size_t ws_size,
                              hipStream_t stream) {
  const int* x = (const int*)d_in[0];
  const int* td = (const int*)d_in[1];
  const int* mask = (const int*)d_in[2];
  const float* ee = (const float*)d_in[3];
  const float* te = (const float*)d_in[4];
  const float* Wq = (const float*)d_in[5];
  const float* bq = (const float*)d_in[6];
  const float* Wk = (const float*)d_in[7];
  const float* bk = (const float*)d_in[8];
  const float* Wv = (const float*)d_in[9];
  const float* bv = (const float*)d_in[10];
  const float* tp = (const float*)d_in[11];
  const float* Wo = (const float*)d_in[12];
  const float* bo = (const float*)d_in[13];
  const float* lng = (const float*)d_in[14];
  const float* lnb = (const float*)d_in[15];
  const float* Wc1 = (const float*)d_in[16];
  const float* bc1 = (const float*)d_in[17];
  const float* Wc2 = (const float*)d_in[18];
  const float* bc2 = (const float*)d_in[19];
  float* out = (float*)d_out;

  float* ws = (float*)d_ws;
  const size_t n = (size_t)NB * NS * ND;   // 2,097,152 floats
  float* h = ws;
  float* qb = ws + n;
  float* kb = ws + 2 * n;
  float* vb = ws + 3 * n;
  float* ctx = ws + 4 * n;

  k_embed<<<NB * NS, ND, 0, stream>>>(x, td, ee, te, h);

  for (int l = 0; l < NL; ++l) {
    const float* Wql = Wq + (size_t)l * ND * ND;
    const float* bql = bq + (size_t)l * ND;
    const float* Wkl = Wk + (size_t)l * ND * ND;
    const float* bkl = bk + (size_t)l * ND;
    const float* Wvl = Wv + (size_t)l * ND * ND;
    const float* bvl = bv + (size_t)l * ND;
    const float* tpl = tp + (size_t)l * NT * NH;
    const float* Wol = Wo + (size_t)l * ND * ND;
    const float* bol = bo + (size_t)l * ND;
    const float* lngl = lng + (size_t)l * ND;
    const float* lnbl = lnb + (size_t)l * ND;

    // K,V needed for all positions in both layers; Q waste in last layer is small
    k_qkv<<<NB * NS / 16, 256, 0, stream>>>(h, Wql, bql, Wkl, bkl, Wvl, bvl, qb, kb, vb);

    const bool lastLayer = (l == NL - 1);
    int q_base = lastLayer ? NS - 16 : 0;
    int ntiles = lastLayer ? 1 : NS / 16;
    dim3 ag(ntiles, NH, NB);
    k_attn<<<ag, 256, 0, stream>>>(qb, kb, vb, td, mask, tpl, ctx, q_base);

    dim3 pg(ntiles, NB);
    k_proj<<<pg, 256, 0, stream>>>(ctx, Wol, bol, h, q_base);

    int lnrows = lastLayer ? 1 : NS;
    int ln_qbase = lastLayer ? NS - 1 : 0;
    dim3 lg(lnrows, NB);
    k_ln<<<lg, 256, 0, stream>>>(h, lngl, lnbl, ln_qbase);
  }

  k_head<<<1, 128, 0, stream>>>(h, Wc1, bc1, Wc2, bc2, out);
}

// Round 2
// 401.436 us; speedup vs baseline: 2.9016x; 2.9016x over previous
//
#include <hip/hip_runtime.h>
#include <math.h>

namespace {

constexpr int NB = 4, NS = 2048, ND = 256, NH = 4, NDK = 64, NL = 2, NT = 1000;

typedef short bfx8 __attribute__((ext_vector_type(8)));
typedef float f32x4 __attribute__((ext_vector_type(4)));

static __device__ __forceinline__ short f2bf(float f) {
  union { float f; unsigned u; } v; v.f = f;
  unsigned u = v.u;
  unsigned r = (u + 0x7fffu + ((u >> 16) & 1u)) >> 16;   // RNE
  return (short)r;
}

// ---------------- embedding gather: h = event_emb[x] + time_emb[clip(td)] ----
__global__ __launch_bounds__(256) void k_embed(const int* __restrict__ x,
                                               const int* __restrict__ td,
                                               const float* __restrict__ ee,
                                               const float* __restrict__ te,
                                               float* __restrict__ h) {
  int row = blockIdx.x;
  int d = threadIdx.x;
  int xi = x[row];
  int tb = td[row];
  tb = tb < 0 ? 0 : (tb >= NT ? NT - 1 : tb);
  h[row * ND + d] = ee[xi * ND + d] + te[tb * ND + d];
}

// ---------------- fused QKV projection: 16-row tile per block ----------------
__global__ __launch_bounds__(256) void k_qkv(const float* __restrict__ h,
                                             const float* __restrict__ Wq, const float* __restrict__ bq,
                                             const float* __restrict__ Wk, const float* __restrict__ bk,
                                             const float* __restrict__ Wv, const float* __restrict__ bv,
                                             float* __restrict__ q, float* __restrict__ k,
                                             float* __restrict__ v) {
  __shared__ float tile[16][ND];
  int col = threadIdx.x;
  int row0 = blockIdx.x * 16;
  #pragma unroll
  for (int r = 0; r < 16; ++r) tile[r][col] = h[(row0 + r) * ND + col];
  __syncthreads();
  float aq[16], ak[16], av[16];
  #pragma unroll
  for (int r = 0; r < 16; ++r) { aq[r] = 0.f; ak[r] = 0.f; av[r] = 0.f; }
  for (int kk = 0; kk < ND; ++kk) {
    float wq = Wq[kk * ND + col];
    float wk = Wk[kk * ND + col];
    float wv = Wv[kk * ND + col];
    #pragma unroll
    for (int r = 0; r < 16; ++r) {
      float hv = tile[r][kk];
      aq[r] = fmaf(hv, wq, aq[r]);
      ak[r] = fmaf(hv, wk, ak[r]);
      av[r] = fmaf(hv, wv, av[r]);
    }
  }
  float bbq = bq[col], bbk = bk[col], bbv = bv[col];
  #pragma unroll
  for (int r = 0; r < 16; ++r) {
    q[(row0 + r) * ND + col] = aq[r] + bbq;
    k[(row0 + r) * ND + col] = ak[r] + bbk;
    v[(row0 + r) * ND + col] = av[r] + bbv;
  }
}

// ---------------- MFMA flash attention ---------------------------------------
// Block: 256 threads = 4 waves; each wave owns 16 queries. QT=64, KT=64.
// QK^T: A=Q[16x32] (bf16 frags from global), B=K^T via row-major K tile in LDS.
// PV:   A=P[16x32] via per-wave LDS tile, B=V via TRANSPOSED V tile in LDS.
__global__ __launch_bounds__(256) void k_attn(const float* __restrict__ q,
                                              const float* __restrict__ k,
                                              const float* __restrict__ v,
                                              const int* __restrict__ td,
                                              const int* __restrict__ mask,
                                              const float* __restrict__ tp,
                                              float* __restrict__ ctx, int q_base) {
  constexpr int KT = 64, LP = 72;  // 72*2B=144B row stride: no pow2 bank conflict
  __shared__ short kt[KT][LP];     // K tile, row-major [key][dim]
  __shared__ short vt[NDK][LP];    // V tile, TRANSPOSED [dim][key]
  __shared__ short pt[4][16][LP];  // per-wave P tile [qrow][key]
  __shared__ float sbias[KT];
  __shared__ int smask[KT];

  int tid = threadIdx.x;
  int w = tid >> 6;
  int lane = tid & 63;
  int ln15 = lane & 15;
  int g = lane >> 4;          // 0..3
  int b = blockIdx.z, hh = blockIdx.y;
  int q0 = q_base + blockIdx.x * 64;
  int qw0 = q0 + w * 16;

  // Q fragments (2 k-steps of 32), loaded once, fp32 -> bf16
  bfx8 aq[2];
  #pragma unroll
  for (int ks = 0; ks < 2; ++ks) {
    const float* qs = &q[(size_t)(b * NS + qw0 + ln15) * ND + hh * NDK + ks * 32 + g * 8];
    float4 f0 = ((const float4*)qs)[0];
    float4 f1 = ((const float4*)qs)[1];
    bfx8 t;
    t[0] = f2bf(f0.x); t[1] = f2bf(f0.y); t[2] = f2bf(f0.z); t[3] = f2bf(f0.w);
    t[4] = f2bf(f1.x); t[5] = f2bf(f1.y); t[6] = f2bf(f1.z); t[7] = f2bf(f1.w);
    aq[ks] = t;
  }

  f32x4 o[4];
  #pragma unroll
  for (int nt = 0; nt < 4; ++nt) o[nt] = (f32x4){0.f, 0.f, 0.f, 0.f};
  float m[4], lsum[4];
  #pragma unroll
  for (int r = 0; r < 4; ++r) { m[r] = -1e30f; lsum[r] = 0.f; }

  int srow = tid >> 2;          // 0..63 staging row
  int scg = (tid & 3) * 16;     // column group

  for (int kb = 0; kb < NS / KT; ++kb) {
    int k0 = kb * KT;
    __syncthreads();  // previous tile fully consumed

    // ---- stage K (row-major) and V (transposed) as bf16 ----
    {
      const float* kr = &k[(size_t)(b * NS + k0 + srow) * ND + hh * NDK + scg];
      const float* vr = &v[(size_t)(b * NS + k0 + srow) * ND + hh * NDK + scg];
      float4 k0v = ((const float4*)kr)[0], k1v = ((const float4*)kr)[1];
      float4 k2v = ((const float4*)kr)[2], k3v = ((const float4*)kr)[3];
      bfx8 p0, p1;
      p0[0]=f2bf(k0v.x); p0[1]=f2bf(k0v.y); p0[2]=f2bf(k0v.z); p0[3]=f2bf(k0v.w);
      p0[4]=f2bf(k1v.x); p0[5]=f2bf(k1v.y); p0[6]=f2bf(k1v.z); p0[7]=f2bf(k1v.w);
      p1[0]=f2bf(k2v.x); p1[1]=f2bf(k2v.y); p1[2]=f2bf(k2v.z); p1[3]=f2bf(k3v.w-(k3v.w-k2v.w));
      p1[3]=f2bf(k2v.w);
      p1[4]=f2bf(k3v.x); p1[5]=f2bf(k3v.y); p1[6]=f2bf(k3v.z); p1[7]=f2bf(k3v.w);
      *(bfx8*)&kt[srow][scg] = p0;
      *(bfx8*)&kt[srow][scg + 8] = p1;
      float4 v0v = ((const float4*)vr)[0], v1v = ((const float4*)vr)[1];
      float4 v2v = ((const float4*)vr)[2], v3v = ((const float4*)vr)[3];
      float vv[16] = {v0v.x, v0v.y, v0v.z, v0v.w, v1v.x, v1v.y, v1v.z, v1v.w,
                      v2v.x, v2v.y, v2v.z, v2v.w, v3v.x, v3v.y, v3v.z, v3v.w};
      #pragma unroll
      for (int i = 0; i < 16; ++i) vt[scg + i][srow] = f2bf(vv[i]);
    }
    if (tid < KT) {
      int key = k0 + tid;
      int tb = td[b * NS + key];
      tb = tb < 0 ? 0 : (tb >= NT ? NT - 1 : tb);
      sbias[tid] = tp[tb * NH + hh];
      smask[tid] = mask[b * NS + key];
    }
    __syncthreads();

    // ---- QK^T: 4 N-tiles x 2 K-steps ----
    f32x4 c[4];
    #pragma unroll
    for (int nt = 0; nt < 4; ++nt) {
      c[nt] = (f32x4){0.f, 0.f, 0.f, 0.f};
      #pragma unroll
      for (int ks = 0; ks < 2; ++ks) {
        bfx8 bk = *(const bfx8*)&kt[nt * 16 + ln15][ks * 32 + g * 8];
        c[nt] = __builtin_amdgcn_mfma_f32_16x16x32_bf16(aq[ks], bk, c[nt], 0, 0, 0);
      }
    }

    // ---- bias + mask + online softmax (rows g*4+r live in this lane) ----
    float sc[4][4];
    #pragma unroll
    for (int nt = 0; nt < 4; ++nt) {
      int kcol = nt * 16 + ln15;
      float bias = sbias[kcol];
      int mk = smask[kcol];
      #pragma unroll
      for (int r = 0; r < 4; ++r) {
        float s = fmaf(c[nt][r], 0.125f, bias);
        sc[nt][r] = mk ? s : -1e9f;
      }
    }
    float rm[4];
    #pragma unroll
    for (int r = 0; r < 4; ++r)
      rm[r] = fmaxf(fmaxf(sc[0][r], sc[1][r]), fmaxf(sc[2][r], sc[3][r]));
    #pragma unroll
    for (int off = 1; off < 16; off <<= 1) {
      #pragma unroll
      for (int r = 0; r < 4; ++r) rm[r] = fmaxf(rm[r], __shfl_xor(rm[r], off, 64));
    }
    float pr[4][4], rs[4];
    #pragma unroll
    for (int r = 0; r < 4; ++r) {
      float mn = fmaxf(m[r], rm[r]);
      float scale = __expf(m[r] - mn);
      m[r] = mn;
      float s0 = 0.f;
      #pragma unroll
      for (int nt = 0; nt < 4; ++nt) { pr[nt][r] = __expf(sc[nt][r] - mn); s0 += pr[nt][r]; }
      rs[r] = s0;
      lsum[r] *= scale;
      #pragma unroll
      for (int nt = 0; nt < 4; ++nt) o[nt][r] *= scale;
    }
    #pragma unroll
    for (int off = 1; off < 16; off <<= 1) {
      #pragma unroll
      for (int r = 0; r < 4; ++r) rs[r] += __shfl_xor(rs[r], off, 64);
    }
    #pragma unroll
    for (int r = 0; r < 4; ++r) lsum[r] += rs[r];

    // ---- write P (bf16) into per-wave LDS tile in A-fragment layout ----
    #pragma unroll
    for (int nt = 0; nt < 4; ++nt) {
      #pragma unroll
      for (int r = 0; r < 4; ++r) pt[w][g * 4 + r][nt * 16 + ln15] = f2bf(pr[nt][r]);
    }

    // ---- PV: o += P(16x64) @ V(64xNDK) via transposed V tile ----
    #pragma unroll
    for (int ks = 0; ks < 2; ++ks) {
      bfx8 pa = *(const bfx8*)&pt[w][ln15][ks * 32 + g * 8];
      #pragma unroll
      for (int nt = 0; nt < 4; ++nt) {
        bfx8 bv = *(const bfx8*)&vt[nt * 16 + ln15][ks * 32 + g * 8];
        o[nt] = __builtin_amdgcn_mfma_f32_16x16x32_bf16(pa, bv, o[nt], 0, 0, 0);
      }
    }
  }

  float inv[4];
  #pragma unroll
  for (int r = 0; r < 4; ++r) inv[r] = 1.f / lsum[r];
  #pragma unroll
  for (int nt = 0; nt < 4; ++nt) {
    #pragma unroll
    for (int r = 0; r < 4; ++r) {
      int qrow = qw0 + g * 4 + r;
      ctx[(size_t)(b * NS + qrow) * ND + hh * NDK + nt * 16 + ln15] = o[nt][r] * inv[r];
    }
  }
}

// ---------------- output projection: out = in @ W + bias ---------------------
__global__ __launch_bounds__(256) void k_proj(const float* __restrict__ in,
                                              const float* __restrict__ W,
                                              const float* __restrict__ bias,
                                              float* __restrict__ out, int q_base) {
  __shared__ float tile[16][ND];
  int col = threadIdx.x;
  int row0 = blockIdx.y * NS + q_base + blockIdx.x * 16;
  #pragma unroll
  for (int r = 0; r < 16; ++r) tile[r][col] = in[(row0 + r) * ND + col];
  __syncthreads();
  float acc[16];
  #pragma unroll
  for (int r = 0; r < 16; ++r) acc[r] = 0.f;
  for (int kk = 0; kk < ND; ++kk) {
    float w = W[kk * ND + col];
    #pragma unroll
    for (int r = 0; r < 16; ++r) acc[r] = fmaf(tile[r][kk], w, acc[r]);
  }
  float bb = bias[col];
  #pragma unroll
  for (int r = 0; r < 16; ++r) out[(row0 + r) * ND + col] = acc[r] + bb;
}

// ---------------- layernorm over D=256, in place -----------------------------
__global__ __launch_bounds__(256) void k_ln(float* __restrict__ h,
                                            const float* __restrict__ g,
                                            const float* __restrict__ bb, int q_base) {
  __shared__ float red[ND];
  int row = blockIdx.y * NS + q_base + blockIdx.x;
  int d = threadIdx.x;
  float val = h[row * ND + d];
  red[d] = val;
  __syncthreads();
  for (int off = 128; off > 0; off >>= 1) {
    if (d < off) red[d] += red[d + off];
    __syncthreads();
  }
  float mu = red[0] * (1.f / ND);
  __syncthreads();
  float diff = val - mu;
  red[d] = diff * diff;
  __syncthreads();
  for (int off = 128; off > 0; off >>= 1) {
    if (d < off) red[d] += red[d + off];
    __syncthreads();
  }
  float var = red[0] * (1.f / ND);
  float r = rsqrtf(var + 1e-5f);
  h[row * ND + d] = diff * r * g[d] + bb[d];
}

// ---------------- classifier head on last token ------------------------------
__global__ __launch_bounds__(128) void k_head(const float* __restrict__ h,
                                              const float* __restrict__ Wc1,
                                              const float* __restrict__ bc1,
                                              const float* __restrict__ Wc2,
                                              const float* __restrict__ bc2,
                                              float* __restrict__ out) {
  __shared__ float red[128];
  int j = threadIdx.x;
  for (int b = 0; b < NB; ++b) {
    const float* last = &h[(size_t)(b * NS + NS - 1) * ND];
    float acc = bc1[j];
    for (int d = 0; d < ND; ++d) acc = fmaf(last[d], Wc1[d * 128 + j], acc);
    acc = fmaxf(acc, 0.f);
    red[j] = acc * Wc2[j];
    __syncthreads();
    for (int off = 64; off > 0; off >>= 1) {
      if (j < off) red[j] += red[j + off];
      __syncthreads();
    }
    if (j == 0) out[b] = 1.f / (1.f + __expf(-(red[0] + bc2[0])));
    __syncthreads();
  }
}

}  // namespace

extern "C" void kernel_launch(void* const* d_in, const int* in_sizes, int n_in,
                              void* d_out, int out_size, void* d_ws, size_t ws_size,
                              hipStream_t stream) {
  const int* x = (const int*)d_in[0];
  const int* td = (const int*)d_in[1];
  const int* mask = (const int*)d_in[2];
  const float* ee = (const float*)d_in[3];
  const float* te = (const float*)d_in[4];
  const float* Wq = (const float*)d_in[5];
  const float* bq = (const float*)d_in[6];
  const float* Wk = (const float*)d_in[7];
  const float* bk = (const float*)d_in[8];
  const float* Wv = (const float*)d_in[9];
  const float* bv = (const float*)d_in[10];
  const float* tp = (const float*)d_in[11];
  const float* Wo = (const float*)d_in[12];
  const float* bo = (const float*)d_in[13];
  const float* lng = (const float*)d_in[14];
  const float* lnb = (const float*)d_in[15];
  const float* Wc1 = (const float*)d_in[16];
  const float* bc1 = (const float*)d_in[17];
  const float* Wc2 = (const float*)d_in[18];
  const float* bc2 = (const float*)d_in[19];
  float* out = (float*)d_out;

  float* ws = (float*)d_ws;
  const size_t n = (size_t)NB * NS * ND;
  float* h = ws;
  float* qb = ws + n;
  float* kb = ws + 2 * n;
  float* vb = ws + 3 * n;
  float* ctx = ws + 4 * n;

  k_embed<<<NB * NS, ND, 0, stream>>>(x, td, ee, te, h);

  for (int l = 0; l < NL; ++l) {
    const float* Wql = Wq + (size_t)l * ND * ND;
    const float* bql = bq + (size_t)l * ND;
    const float* Wkl = Wk + (size_t)l * ND * ND;
    const float* bkl = bk + (size_t)l * ND;
    const float* Wvl = Wv + (size_t)l * ND * ND;
    const float* bvl = bv + (size_t)l * ND;
    const float* tpl = tp + (size_t)l * NT * NH;
    const float* Wol = Wo + (size_t)l * ND * ND;
    const float* bol = bo + (size_t)l * ND;
    const float* lngl = lng + (size_t)l * ND;
    const float* lnbl = lnb + (size_t)l * ND;

    k_qkv<<<NB * NS / 16, 256, 0, stream>>>(h, Wql, bql, Wkl, bkl, Wvl, bvl, qb, kb, vb);

    const bool lastLayer = (l == NL - 1);
    int qtiles = lastLayer ? 1 : NS / 64;
    int aq_base = lastLayer ? NS - 64 : 0;
    dim3 ag(qtiles, NH, NB);
    k_attn<<<ag, 256, 0, stream>>>(qb, kb, vb, td, mask, tpl, ctx, aq_base);

    int ptiles = lastLayer ? 1 : NS / 16;
    int pq_base = lastLayer ? NS - 16 : 0;
    dim3 pg(ptiles, NB);
    k_proj<<<pg, 256, 0, stream>>>(ctx, Wol, bol, h, pq_base);

    int lnrows = lastLayer ? 1 : NS;
    int ln_qbase = lastLayer ? NS - 1 : 0;
    dim3 lg(lnrows, NB);
    k_ln<<<lg, 256, 0, stream>>>(h, lngl, lnbl, ln_qbase);
  }

  k_head<<<1, 128, 0, stream>>>(h, Wc1, bc1, Wc2, bc2, out);
}

// Round 3
// 267.519 us; speedup vs baseline: 4.3540x; 1.5006x over previous
//
#include <hip/hip_runtime.h>
#include <math.h>

namespace {

constexpr int NB = 4, NS = 2048, ND = 256, NH = 4, NDK = 64, NL = 2, NT = 1000;

typedef short bfx8 __attribute__((ext_vector_type(8)));
typedef float f32x4 __attribute__((ext_vector_type(4)));

static __device__ __forceinline__ short f2bf(float f) {
  union { float f; unsigned u; } v; v.f = f;
  unsigned u = v.u;
  unsigned r = (u + 0x7fffu + ((u >> 16) & 1u)) >> 16;   // RNE
  return (short)r;
}
static __device__ __forceinline__ float bf2f(short s) {
  union { float f; unsigned u; } v; v.u = ((unsigned)(unsigned short)s) << 16;
  return v.f;
}

// ---------------- weight pack: W[K][N] fp32 -> WT[N][K] bf16 -----------------
__global__ __launch_bounds__(256) void k_packw(const float* __restrict__ Wq,
                                               const float* __restrict__ Wk,
                                               const float* __restrict__ Wv,
                                               const float* __restrict__ Wo,
                                               short* __restrict__ wqkvT,
                                               short* __restrict__ woT) {
  __shared__ float t[64][65];
  int z = blockIdx.z, l = z >> 2, mat = z & 3;
  const float* src;
  short* dst;
  if (mat == 0)      { src = Wq + (size_t)l * 65536; dst = wqkvT + (size_t)l * 768 * 256; }
  else if (mat == 1) { src = Wk + (size_t)l * 65536; dst = wqkvT + (size_t)l * 768 * 256 + 256 * 256; }
  else if (mat == 2) { src = Wv + (size_t)l * 65536; dst = wqkvT + (size_t)l * 768 * 256 + 512 * 256; }
  else               { src = Wo + (size_t)l * 65536; dst = woT + (size_t)l * 65536; }
  int k0 = blockIdx.x * 64, n0 = blockIdx.y * 64;
  int c = threadIdx.x & 63, r4 = threadIdx.x >> 6;
  #pragma unroll
  for (int rr = 0; rr < 64; rr += 4) t[rr + r4][c] = src[(size_t)(k0 + rr + r4) * 256 + n0 + c];
  __syncthreads();
  #pragma unroll
  for (int rr = 0; rr < 64; rr += 4) {
    int n = rr + r4;
    dst[(size_t)(n0 + n) * 256 + k0 + c] = f2bf(t[c][n]);
  }
}

__global__ __launch_bounds__(768) void k_packb(const float* __restrict__ bq,
                                               const float* __restrict__ bk,
                                               const float* __restrict__ bv,
                                               float* __restrict__ bqkv) {
  int l = blockIdx.x, c = threadIdx.x;
  float v;
  if (c < 256) v = bq[l * 256 + c];
  else if (c < 512) v = bk[l * 256 + c - 256];
  else v = bv[l * 256 + c - 512];
  bqkv[l * 768 + c] = v;
}

// ---------------- embedding gather -------------------------------------------
__global__ __launch_bounds__(256) void k_embed(const int* __restrict__ x,
                                               const int* __restrict__ td,
                                               const float* __restrict__ ee,
                                               const float* __restrict__ te,
                                               float* __restrict__ h,
                                               short* __restrict__ hb) {
  int row = blockIdx.x;
  int d = threadIdx.x;
  int xi = x[row];
  int tb = td[row];
  tb = tb < 0 ? 0 : (tb >= NT ? NT - 1 : tb);
  float v = ee[(size_t)xi * ND + d] + te[(size_t)tb * ND + d];
  h[(size_t)row * ND + d] = v;
  hb[(size_t)row * ND + d] = f2bf(v);
}

// ---------------- MFMA GEMM: C[M][N] = A[M][256] @ WT^T + bias ---------------
// A bf16 [M][256]; BT bf16 [N][256] (transposed weights); tile 64x64, BK=64.
template <int OUT_BF16>
__global__ __launch_bounds__(256) void k_gemm(const short* __restrict__ A,
                                              const short* __restrict__ BT,
                                              const float* __restrict__ bias,
                                              void* __restrict__ C, int ldc,
                                              int mb_mul, int mb_add, int n_base) {
  constexpr int LP = 76;  // 38-dword row stride: 16 frag rows -> 16 distinct banks
  __shared__ short at[64][LP];
  __shared__ short bt[64][LP];
  int tid = threadIdx.x;
  int w = tid >> 6, lane = tid & 63, ln15 = lane & 15, g = lane >> 4;
  int m0 = (blockIdx.x * mb_mul + mb_add) * 64;
  int n0 = n_base + blockIdx.y * 64;
  int srow = tid >> 2, scol = (tid & 3) * 16;

  f32x4 acc[4];
  #pragma unroll
  for (int nt = 0; nt < 4; ++nt) acc[nt] = (f32x4){0.f, 0.f, 0.f, 0.f};

  for (int kk0 = 0; kk0 < 256; kk0 += 64) {
    __syncthreads();
    const short* as = &A[(size_t)(m0 + srow) * 256 + kk0 + scol];
    const short* bs = &BT[(size_t)(n0 + srow) * 256 + kk0 + scol];
    bfx8 a0 = *(const bfx8*)as, a1 = *(const bfx8*)(as + 8);
    bfx8 b0 = *(const bfx8*)bs, b1 = *(const bfx8*)(bs + 8);
    *(bfx8*)&at[srow][scol] = a0; *(bfx8*)&at[srow][scol + 8] = a1;
    *(bfx8*)&bt[srow][scol] = b0; *(bfx8*)&bt[srow][scol + 8] = b1;
    __syncthreads();
    #pragma unroll
    for (int ks = 0; ks < 2; ++ks) {
      bfx8 af = *(const bfx8*)&at[w * 16 + ln15][ks * 32 + g * 8];
      #pragma unroll
      for (int nt = 0; nt < 4; ++nt) {
        bfx8 bf = *(const bfx8*)&bt[nt * 16 + ln15][ks * 32 + g * 8];
        acc[nt] = __builtin_amdgcn_mfma_f32_16x16x32_bf16(af, bf, acc[nt], 0, 0, 0);
      }
    }
  }

  #pragma unroll
  for (int nt = 0; nt < 4; ++nt) {
    int col = n0 + nt * 16 + ln15;
    float bb = bias[col];
    #pragma unroll
    for (int r = 0; r < 4; ++r) {
      int row = m0 + w * 16 + g * 4 + r;
      float val = acc[nt][r] + bb;
      if (OUT_BF16) ((short*)C)[(size_t)row * ldc + col] = f2bf(val);
      else          ((float*)C)[(size_t)row * ldc + col] = val;
    }
  }
}

// ---------------- MFMA flash attention (bf16 in/out) --------------------------
__global__ __launch_bounds__(256) void k_attn(const short* __restrict__ qkv,
                                              const int* __restrict__ td,
                                              const int* __restrict__ mask,
                                              const float* __restrict__ tp,
                                              short* __restrict__ ctx, int q_base) {
  constexpr int KT = 64, LP = 76;
  __shared__ short kt[KT][LP];     // K tile [key][dim]
  __shared__ short vt[NDK][LP];    // V tile transposed [dim][key]
  __shared__ short pt[4][16][LP];  // per-wave P tile [qrow][key]
  __shared__ float sbias[KT];
  __shared__ int smask[KT];

  int tid = threadIdx.x;
  int w = tid >> 6;
  int lane = tid & 63;
  int ln15 = lane & 15;
  int g = lane >> 4;
  int b = blockIdx.z, hh = blockIdx.y;
  int q0 = q_base + blockIdx.x * 64;
  int qw0 = q0 + w * 16;

  // Q fragments, bf16 direct
  bfx8 aq[2];
  #pragma unroll
  for (int ks = 0; ks < 2; ++ks)
    aq[ks] = *(const bfx8*)&qkv[(size_t)(b * NS + qw0 + ln15) * 768 + hh * NDK + ks * 32 + g * 8];

  f32x4 o[4];
  #pragma unroll
  for (int nt = 0; nt < 4; ++nt) o[nt] = (f32x4){0.f, 0.f, 0.f, 0.f};
  float m[4], lsum[4];
  #pragma unroll
  for (int r = 0; r < 4; ++r) { m[r] = -1e30f; lsum[r] = 0.f; }

  int srow = tid >> 2, scg = (tid & 3) * 16;   // K staging
  int vw = tid >> 6;                            // V staging: dim group = wave

  for (int kb = 0; kb < NS / KT; ++kb) {
    int k0 = kb * KT;
    __syncthreads();

    // K tile: row-major copy, vectorized
    {
      const short* ks_ = &qkv[(size_t)(b * NS + k0 + srow) * 768 + 256 + hh * NDK + scg];
      bfx8 p0 = *(const bfx8*)ks_, p1 = *(const bfx8*)(ks_ + 8);
      *(bfx8*)&kt[srow][scg] = p0;
      *(bfx8*)&kt[srow][scg + 8] = p1;
    }
    // V tile transposed: lane = key, wave = 16-dim group; bank = lane>>1 (2-way, free)
    {
      const short* vs = &qkv[(size_t)(b * NS + k0 + lane) * 768 + 512 + hh * NDK + vw * 16];
      bfx8 v0 = *(const bfx8*)vs, v1 = *(const bfx8*)(vs + 8);
      #pragma unroll
      for (int i = 0; i < 8; ++i) vt[vw * 16 + i][lane] = v0[i];
      #pragma unroll
      for (int i = 0; i < 8; ++i) vt[vw * 16 + 8 + i][lane] = v1[i];
    }
    if (tid < KT) {
      int key = k0 + tid;
      int tb = td[b * NS + key];
      tb = tb < 0 ? 0 : (tb >= NT ? NT - 1 : tb);
      sbias[tid] = tp[tb * NH + hh];
      smask[tid] = mask[b * NS + key];
    }
    __syncthreads();

    // QK^T
    f32x4 c[4];
    #pragma unroll
    for (int nt = 0; nt < 4; ++nt) {
      c[nt] = (f32x4){0.f, 0.f, 0.f, 0.f};
      #pragma unroll
      for (int ks = 0; ks < 2; ++ks) {
        bfx8 bk = *(const bfx8*)&kt[nt * 16 + ln15][ks * 32 + g * 8];
        c[nt] = __builtin_amdgcn_mfma_f32_16x16x32_bf16(aq[ks], bk, c[nt], 0, 0, 0);
      }
    }

    // bias + mask + online softmax
    float sc[4][4];
    #pragma unroll
    for (int nt = 0; nt < 4; ++nt) {
      int kcol = nt * 16 + ln15;
      float bias = sbias[kcol];
      int mk = smask[kcol];
      #pragma unroll
      for (int r = 0; r < 4; ++r) {
        float s = fmaf(c[nt][r], 0.125f, bias);
        sc[nt][r] = mk ? s : -1e9f;
      }
    }
    float rm[4];
    #pragma unroll
    for (int r = 0; r < 4; ++r)
      rm[r] = fmaxf(fmaxf(sc[0][r], sc[1][r]), fmaxf(sc[2][r], sc[3][r]));
    #pragma unroll
    for (int off = 1; off < 16; off <<= 1) {
      #pragma unroll
      for (int r = 0; r < 4; ++r) rm[r] = fmaxf(rm[r], __shfl_xor(rm[r], off, 64));
    }
    float pr[4][4], rs[4];
    #pragma unroll
    for (int r = 0; r < 4; ++r) {
      float mn = fmaxf(m[r], rm[r]);
      float scale = __expf(m[r] - mn);
      m[r] = mn;
      float s0 = 0.f;
      #pragma unroll
      for (int nt = 0; nt < 4; ++nt) { pr[nt][r] = __expf(sc[nt][r] - mn); s0 += pr[nt][r]; }
      rs[r] = s0;
      lsum[r] *= scale;
      #pragma unroll
      for (int nt = 0; nt < 4; ++nt) o[nt][r] *= scale;
    }
    #pragma unroll
    for (int off = 1; off < 16; off <<= 1) {
      #pragma unroll
      for (int r = 0; r < 4; ++r) rs[r] += __shfl_xor(rs[r], off, 64);
    }
    #pragma unroll
    for (int r = 0; r < 4; ++r) lsum[r] += rs[r];

    // P -> per-wave LDS tile (2-way banks, free)
    #pragma unroll
    for (int nt = 0; nt < 4; ++nt) {
      #pragma unroll
      for (int r = 0; r < 4; ++r) pt[w][g * 4 + r][nt * 16 + ln15] = f2bf(pr[nt][r]);
    }

    // PV
    #pragma unroll
    for (int ks = 0; ks < 2; ++ks) {
      bfx8 pa = *(const bfx8*)&pt[w][ln15][ks * 32 + g * 8];
      #pragma unroll
      for (int nt = 0; nt < 4; ++nt) {
        bfx8 bv = *(const bfx8*)&vt[nt * 16 + ln15][ks * 32 + g * 8];
        o[nt] = __builtin_amdgcn_mfma_f32_16x16x32_bf16(pa, bv, o[nt], 0, 0, 0);
      }
    }
  }

  float inv[4];
  #pragma unroll
  for (int r = 0; r < 4; ++r) inv[r] = 1.f / lsum[r];
  #pragma unroll
  for (int nt = 0; nt < 4; ++nt) {
    #pragma unroll
    for (int r = 0; r < 4; ++r) {
      int qrow = qw0 + g * 4 + r;
      ctx[(size_t)(b * NS + qrow) * ND + hh * NDK + nt * 16 + ln15] = f2bf(o[nt][r] * inv[r]);
    }
  }
}

// ---------------- layernorm: h fp32 in -> h fp32 + hb bf16 -------------------
__global__ __launch_bounds__(256) void k_ln(float* __restrict__ h,
                                            short* __restrict__ hb,
                                            const float* __restrict__ g,
                                            const float* __restrict__ bb, int q_base) {
  __shared__ float red[ND];
  size_t row = (size_t)blockIdx.y * NS + q_base + blockIdx.x;
  int d = threadIdx.x;
  float val = h[row * ND + d];
  red[d] = val;
  __syncthreads();
  for (int off = 128; off > 0; off >>= 1) {
    if (d < off) red[d] += red[d + off];
    __syncthreads();
  }
  float mu = red[0] * (1.f / ND);
  __syncthreads();
  float diff = val - mu;
  red[d] = diff * diff;
  __syncthreads();
  for (int off = 128; off > 0; off >>= 1) {
    if (d < off) red[d] += red[d + off];
    __syncthreads();
  }
  float var = red[0] * (1.f / ND);
  float r = rsqrtf(var + 1e-5f);
  float o = diff * r * g[d] + bb[d];
  h[row * ND + d] = o;
  hb[row * ND + d] = f2bf(o);
}

// ---------------- classifier head on last token ------------------------------
__global__ __launch_bounds__(128) void k_head(const float* __restrict__ h,
                                              const float* __restrict__ Wc1,
                                              const float* __restrict__ bc1,
                                              const float* __restrict__ Wc2,
                                              const float* __restrict__ bc2,
                                              float* __restrict__ out) {
  __shared__ float red[128];
  int j = threadIdx.x;
  for (int b = 0; b < NB; ++b) {
    const float* last = &h[(size_t)(b * NS + NS - 1) * ND];
    float acc = bc1[j];
    for (int d = 0; d < ND; ++d) acc = fmaf(last[d], Wc1[d * 128 + j], acc);
    acc = fmaxf(acc, 0.f);
    red[j] = acc * Wc2[j];
    __syncthreads();
    for (int off = 64; off > 0; off >>= 1) {
      if (j < off) red[j] += red[j + off];
      __syncthreads();
    }
    if (j == 0) out[b] = 1.f / (1.f + __expf(-(red[0] + bc2[0])));
    __syncthreads();
  }
}

}  // namespace

extern "C" void kernel_launch(void* const* d_in, const int* in_sizes, int n_in,
                              void* d_out, int out_size, void* d_ws, size_t ws_size,
                              hipStream_t stream) {
  const int* x = (const int*)d_in[0];
  const int* td = (const int*)d_in[1];
  const int* mask = (const int*)d_in[2];
  const float* ee = (const float*)d_in[3];
  const float* te = (const float*)d_in[4];
  const float* Wq = (const float*)d_in[5];
  const float* bq = (const float*)d_in[6];
  const float* Wk = (const float*)d_in[7];
  const float* bk = (const float*)d_in[8];
  const float* Wv = (const float*)d_in[9];
  const float* bv = (const float*)d_in[10];
  const float* tp = (const float*)d_in[11];
  const float* Wo = (const float*)d_in[12];
  const float* bo = (const float*)d_in[13];
  const float* lng = (const float*)d_in[14];
  const float* lnb = (const float*)d_in[15];
  const float* Wc1 = (const float*)d_in[16];
  const float* bc1 = (const float*)d_in[17];
  const float* Wc2 = (const float*)d_in[18];
  const float* bc2 = (const float*)d_in[19];
  float* out = (float*)d_out;

  char* ws = (char*)d_ws;
  const size_t M = (size_t)NB * NS;  // 8192
  float* h     = (float*)(ws);                       // 8 MB
  short* hb    = (short*)(ws + (8 << 20));           // 4 MB
  short* qkv   = (short*)(ws + (12 << 20));          // 12 MB  [M][768]
  short* ctx   = (short*)(ws + (24 << 20));          // 4 MB   [M][256]
  short* wqkvT = (short*)(ws + (28 << 20));          // 768 KB [2][768][256]
  short* woT   = (short*)(ws + (28 << 20) + 786432); // 256 KB [2][256][256]
  float* bqkv  = (float*)(ws + (29 << 20) + 262144); // 6 KB   [2][768]

  k_packw<<<dim3(4, 4, 8), 256, 0, stream>>>(Wq, Wk, Wv, Wo, wqkvT, woT);
  k_packb<<<2, 768, 0, stream>>>(bq, bk, bv, bqkv);
  k_embed<<<NB * NS, ND, 0, stream>>>(x, td, ee, te, h, hb);

  for (int l = 0; l < NL; ++l) {
    const short* wqkvTl = wqkvT + (size_t)l * 768 * 256;
    const short* woTl = woT + (size_t)l * 65536;
    const float* bqkvl = bqkv + (size_t)l * 768;
    const float* bol = bo + (size_t)l * ND;
    const float* tpl = tp + (size_t)l * NT * NH;
    const float* lngl = lng + (size_t)l * ND;
    const float* lnbl = lnb + (size_t)l * ND;
    const bool last = (l == NL - 1);

    if (!last) {
      k_gemm<1><<<dim3(M / 64, 12), 256, 0, stream>>>(hb, wqkvTl, bqkvl, qkv, 768, 1, 0, 0);
    } else {
      // K,V for all rows; Q only for the 64-row block containing each batch's last token
      k_gemm<1><<<dim3(M / 64, 8), 256, 0, stream>>>(hb, wqkvTl, bqkvl, qkv, 768, 1, 0, 256);
      k_gemm<1><<<dim3(NB, 4), 256, 0, stream>>>(hb, wqkvTl, bqkvl, qkv, 768, 32, 31, 0);
    }

    int qtiles = last ? 1 : NS / 64;
    int aq_base = last ? NS - 64 : 0;
    k_attn<<<dim3(qtiles, NH, NB), 256, 0, stream>>>(qkv, td, mask, tpl, ctx, aq_base);

    if (!last) {
      k_gemm<0><<<dim3(M / 64, 4), 256, 0, stream>>>(ctx, woTl, bol, h, 256, 1, 0, 0);
      k_ln<<<dim3(NS, NB), 256, 0, stream>>>(h, hb, lngl, lnbl, 0);
    } else {
      k_gemm<0><<<dim3(NB, 4), 256, 0, stream>>>(ctx, woTl, bol, h, 256, 32, 31, 0);
      k_ln<<<dim3(1, NB), 256, 0, stream>>>(h, hb, lngl, lnbl, NS - 1);
    }
  }

  k_head<<<1, 128, 0, stream>>>(h, Wc1, bc1, Wc2, bc2, out);
}

// Round 4
// 190.829 us; speedup vs baseline: 6.1039x; 1.4019x over previous
//
#include <hip/hip_runtime.h>
#include <math.h>

namespace {

constexpr int NB = 4, NS = 2048, ND = 256, NH = 4, NDK = 64, NL = 2, NT = 1000;

typedef short bfx8 __attribute__((ext_vector_type(8)));
typedef float f32x4 __attribute__((ext_vector_type(4)));

static __device__ __forceinline__ short f2bf(float f) {
  union { float f; unsigned u; } v; v.f = f;
  unsigned u = v.u;
  unsigned r = (u + 0x7fffu + ((u >> 16) & 1u)) >> 16;   // RNE
  return (short)r;
}

// ---------------- weight pack: W[K][N] fp32 -> WT[N][K] bf16 -----------------
__global__ __launch_bounds__(256) void k_packw(const float* __restrict__ Wq,
                                               const float* __restrict__ Wk,
                                               const float* __restrict__ Wv,
                                               const float* __restrict__ Wo,
                                               short* __restrict__ wqkvT,
                                               short* __restrict__ woT) {
  __shared__ float t[64][65];
  int z = blockIdx.z, l = z >> 2, mat = z & 3;
  const float* src;
  short* dst;
  if (mat == 0)      { src = Wq + (size_t)l * 65536; dst = wqkvT + (size_t)l * 768 * 256; }
  else if (mat == 1) { src = Wk + (size_t)l * 65536; dst = wqkvT + (size_t)l * 768 * 256 + 256 * 256; }
  else if (mat == 2) { src = Wv + (size_t)l * 65536; dst = wqkvT + (size_t)l * 768 * 256 + 512 * 256; }
  else               { src = Wo + (size_t)l * 65536; dst = woT + (size_t)l * 65536; }
  int k0 = blockIdx.x * 64, n0 = blockIdx.y * 64;
  int c = threadIdx.x & 63, r4 = threadIdx.x >> 6;
  #pragma unroll
  for (int rr = 0; rr < 64; rr += 4) t[rr + r4][c] = src[(size_t)(k0 + rr + r4) * 256 + n0 + c];
  __syncthreads();
  #pragma unroll
  for (int rr = 0; rr < 64; rr += 4) {
    int n = rr + r4;
    dst[(size_t)(n0 + n) * 256 + k0 + c] = f2bf(t[c][n]);
  }
}

__global__ __launch_bounds__(768) void k_packb(const float* __restrict__ bq,
                                               const float* __restrict__ bk,
                                               const float* __restrict__ bv,
                                               float* __restrict__ bqkv) {
  int l = blockIdx.x, c = threadIdx.x;
  float v;
  if (c < 256) v = bq[l * 256 + c];
  else if (c < 512) v = bk[l * 256 + c - 256];
  else v = bv[l * 256 + c - 512];
  bqkv[l * 768 + c] = v;
}

// ---------------- embedding gather (float4, 4 rows/block) --------------------
__global__ __launch_bounds__(256) void k_embed(const int* __restrict__ x,
                                               const int* __restrict__ td,
                                               const float* __restrict__ ee,
                                               const float* __restrict__ te,
                                               float* __restrict__ h,
                                               short* __restrict__ hb) {
  int lane = threadIdx.x & 63, r4 = threadIdx.x >> 6;
  int row = blockIdx.x * 4 + r4;
  int xi = x[row];
  int tb = td[row];
  tb = tb < 0 ? 0 : (tb >= NT ? NT - 1 : tb);
  float4 e = ((const float4*)&ee[(size_t)xi * ND])[lane];
  float4 tv = ((const float4*)&te[(size_t)tb * ND])[lane];
  float4 v;
  v.x = e.x + tv.x; v.y = e.y + tv.y; v.z = e.z + tv.z; v.w = e.w + tv.w;
  ((float4*)&h[(size_t)row * ND])[lane] = v;
  short4 ob; ob.x = f2bf(v.x); ob.y = f2bf(v.y); ob.z = f2bf(v.z); ob.w = f2bf(v.w);
  ((short4*)&hb[(size_t)row * ND])[lane] = ob;
}

// ---------------- MFMA GEMM: C[M][N] = A[M][256] @ WT^T + bias ---------------
template <int OUT_BF16>
__global__ __launch_bounds__(256) void k_gemm(const short* __restrict__ A,
                                              const short* __restrict__ BT,
                                              const float* __restrict__ bias,
                                              void* __restrict__ C, int ldc,
                                              int mb_mul, int mb_add, int n_base) {
  constexpr int LP = 76;
  __shared__ short at[64][LP];
  __shared__ short bt[64][LP];
  int tid = threadIdx.x;
  int w = tid >> 6, lane = tid & 63, ln15 = lane & 15, g = lane >> 4;
  int m0 = (blockIdx.x * mb_mul + mb_add) * 64;
  int n0 = n_base + blockIdx.y * 64;
  int srow = tid >> 2, scol = (tid & 3) * 16;

  f32x4 acc[4];
  #pragma unroll
  for (int nt = 0; nt < 4; ++nt) acc[nt] = (f32x4){0.f, 0.f, 0.f, 0.f};

  bfx8 a0, a1, b0, b1;
  auto LOAD = [&](int kk0) {
    const short* as = &A[(size_t)(m0 + srow) * 256 + kk0 + scol];
    const short* bs = &BT[(size_t)(n0 + srow) * 256 + kk0 + scol];
    a0 = *(const bfx8*)as; a1 = *(const bfx8*)(as + 8);
    b0 = *(const bfx8*)bs; b1 = *(const bfx8*)(bs + 8);
  };
  LOAD(0);
  for (int kk0 = 0; kk0 < 256; kk0 += 64) {
    __syncthreads();
    *(bfx8*)&at[srow][scol] = a0; *(bfx8*)&at[srow][scol + 8] = a1;
    *(bfx8*)&bt[srow][scol] = b0; *(bfx8*)&bt[srow][scol + 8] = b1;
    if (kk0 + 64 < 256) LOAD(kk0 + 64);
    __syncthreads();
    #pragma unroll
    for (int ks = 0; ks < 2; ++ks) {
      bfx8 af = *(const bfx8*)&at[w * 16 + ln15][ks * 32 + g * 8];
      #pragma unroll
      for (int nt = 0; nt < 4; ++nt) {
        bfx8 bf = *(const bfx8*)&bt[nt * 16 + ln15][ks * 32 + g * 8];
        acc[nt] = __builtin_amdgcn_mfma_f32_16x16x32_bf16(af, bf, acc[nt], 0, 0, 0);
      }
    }
  }

  #pragma unroll
  for (int nt = 0; nt < 4; ++nt) {
    int col = n0 + nt * 16 + ln15;
    float bb = bias[col];
    #pragma unroll
    for (int r = 0; r < 4; ++r) {
      int row = m0 + w * 16 + g * 4 + r;
      float val = acc[nt][r] + bb;
      if (OUT_BF16) ((short*)C)[(size_t)row * ldc + col] = f2bf(val);
      else          ((float*)C)[(size_t)row * ldc + col] = val;
    }
  }
}

// ---------------- MFMA flash attention, in-block KV-split --------------------
// 512 threads = 8 waves. Wave w: wsub=w&3 owns 16 queries, half=w>>2 owns half
// the KV range. lsum via all-ones V column (PV nt=4). End: LDS merge of halves.
__global__ __launch_bounds__(512, 4) void k_attn(const short* __restrict__ qkv,
                                                 const int* __restrict__ td,
                                                 const int* __restrict__ mask,
                                                 const float* __restrict__ tp,
                                                 short* __restrict__ ctx, int q_base) {
  constexpr int LP = 76;
  __shared__ short kt[2][64][LP];
  __shared__ short vt[2][80][LP];   // rows 64..79: ones column (dim 64) + zeros
  __shared__ short pt[8][16][LP];
  __shared__ float sbias[2][64];
  __shared__ int smask[2][64];

  int tid = threadIdx.x;
  int w = tid >> 6, lane = tid & 63, ln15 = lane & 15, g = lane >> 4;
  int half = w >> 2, wsub = w & 3;
  int t = tid & 255;
  int b = blockIdx.z, hh = blockIdx.y;
  int q0 = q_base + blockIdx.x * 64;
  int qw0 = q0 + wsub * 16;

  int srow = t >> 2, scg = (t & 3) * 16;
  int vlane = t & 63, vw = (t >> 6) & 3;

  // ones/zeros rows of vt (never restaged)
  for (int idx = tid; idx < 2 * 16 * LP; idx += 512) {
    int h2 = idx / (16 * LP), rem = idx % (16 * LP), j = rem / LP, c = rem % LP;
    vt[h2][64 + j][c] = (j == 0 && c < 64) ? (short)0x3F80 : (short)0;
  }

  bfx8 aq[2];
  #pragma unroll
  for (int ks = 0; ks < 2; ++ks)
    aq[ks] = *(const bfx8*)&qkv[(size_t)(b * NS + qw0 + ln15) * 768 + hh * NDK + ks * 32 + g * 8];

  f32x4 o[5];
  #pragma unroll
  for (int nt = 0; nt < 5; ++nt) o[nt] = (f32x4){0.f, 0.f, 0.f, 0.f};
  float m[4];
  #pragma unroll
  for (int r = 0; r < 4; ++r) m[r] = -1e30f;

  bfx8 kr0, kr1, vr0, vr1;
  float br = 0.f; int mr = 0;
  auto LOAD = [&](int it) {
    int k0 = (half * 16 + it) * 64;
    const short* ksrc = &qkv[(size_t)(b * NS + k0 + srow) * 768 + 256 + hh * NDK + scg];
    kr0 = *(const bfx8*)ksrc; kr1 = *(const bfx8*)(ksrc + 8);
    const short* vsrc = &qkv[(size_t)(b * NS + k0 + vlane) * 768 + 512 + hh * NDK + vw * 16];
    vr0 = *(const bfx8*)vsrc; vr1 = *(const bfx8*)(vsrc + 8);
    if (t < 64) {
      int key = k0 + t;
      int tb = td[b * NS + key];
      tb = tb < 0 ? 0 : (tb >= NT ? NT - 1 : tb);
      br = tp[tb * NH + hh];
      mr = mask[b * NS + key];
    }
  };
  LOAD(0);

  for (int it = 0; it < 16; ++it) {
    __syncthreads();   // previous tile fully consumed by all waves
    *(bfx8*)&kt[half][srow][scg] = kr0;
    *(bfx8*)&kt[half][srow][scg + 8] = kr1;
    #pragma unroll
    for (int i = 0; i < 8; ++i) {
      vt[half][vw * 16 + i][vlane] = vr0[i];
      vt[half][vw * 16 + 8 + i][vlane] = vr1[i];
    }
    if (t < 64) { sbias[half][t] = br; smask[half][t] = mr; }
    if (it + 1 < 16) LOAD(it + 1);   // prefetch overlaps compute below
    __syncthreads();

    // QK^T
    f32x4 c[4];
    #pragma unroll
    for (int nt = 0; nt < 4; ++nt) {
      c[nt] = (f32x4){0.f, 0.f, 0.f, 0.f};
      #pragma unroll
      for (int ks = 0; ks < 2; ++ks) {
        bfx8 bk = *(const bfx8*)&kt[half][nt * 16 + ln15][ks * 32 + g * 8];
        c[nt] = __builtin_amdgcn_mfma_f32_16x16x32_bf16(aq[ks], bk, c[nt], 0, 0, 0);
      }
    }

    // bias + mask
    float sc[4][4];
    #pragma unroll
    for (int nt = 0; nt < 4; ++nt) {
      int kcol = nt * 16 + ln15;
      float bias = sbias[half][kcol];
      int mk = smask[half][kcol];
      #pragma unroll
      for (int r = 0; r < 4; ++r) {
        float s = fmaf(c[nt][r], 0.125f, bias);
        sc[nt][r] = mk ? s : -1e9f;
      }
    }
    // row max
    float rm[4];
    #pragma unroll
    for (int r = 0; r < 4; ++r)
      rm[r] = fmaxf(fmaxf(sc[0][r], sc[1][r]), fmaxf(sc[2][r], sc[3][r]));
    #pragma unroll
    for (int off = 1; off < 16; off <<= 1) {
      #pragma unroll
      for (int r = 0; r < 4; ++r) rm[r] = fmaxf(rm[r], __shfl_xor(rm[r], off, 64));
    }
    // defer-max: only rescale when max grew by > 8
    bool need = false;
    float nm[4];
    #pragma unroll
    for (int r = 0; r < 4; ++r) {
      nm[r] = fmaxf(m[r], rm[r]);
      need = need || (rm[r] > m[r] + 8.f);
    }
    if (__any(need)) {
      #pragma unroll
      for (int r = 0; r < 4; ++r) {
        float scl = __expf(m[r] - nm[r]);
        m[r] = nm[r];
        #pragma unroll
        for (int nt = 0; nt < 5; ++nt) o[nt][r] *= scl;
      }
    }
    // P (bounded by e^8) -> per-wave LDS tile
    #pragma unroll
    for (int nt = 0; nt < 4; ++nt) {
      #pragma unroll
      for (int r = 0; r < 4; ++r)
        pt[w][g * 4 + r][nt * 16 + ln15] = f2bf(__expf(sc[nt][r] - m[r]));
    }
    // PV (+ ones column accumulates lsum into o[4] col 0)
    #pragma unroll
    for (int ks = 0; ks < 2; ++ks) {
      bfx8 pa = *(const bfx8*)&pt[w][ln15][ks * 32 + g * 8];
      #pragma unroll
      for (int nt = 0; nt < 5; ++nt) {
        bfx8 bv = *(const bfx8*)&vt[half][nt * 16 + ln15][ks * 32 + g * 8];
        o[nt] = __builtin_amdgcn_mfma_f32_16x16x32_bf16(pa, bv, o[nt], 0, 0, 0);
      }
    }
  }

  // broadcast lsum (lives in ln15==0 lanes of o[4])
  float l[4];
  #pragma unroll
  for (int r = 0; r < 4; ++r) l[r] = __shfl(o[4][r], lane & 48, 64);

  __syncthreads();   // kt/sbias free for reuse
  float* shO = (float*)&kt[0][0][0];   // [64 rows][64 cols] fp32 = 16 KB
  float* shML = &sbias[0][0];          // [64 rows][2]
  if (half == 1) {
    #pragma unroll
    for (int nt = 0; nt < 4; ++nt) {
      #pragma unroll
      for (int r = 0; r < 4; ++r)
        shO[(wsub * 16 + g * 4 + r) * 64 + nt * 16 + ln15] = o[nt][r];
    }
    if (ln15 == 0) {
      #pragma unroll
      for (int r = 0; r < 4; ++r) {
        int grow = wsub * 16 + g * 4 + r;
        shML[grow * 2] = m[r];
        shML[grow * 2 + 1] = l[r];
      }
    }
  }
  __syncthreads();
  if (half == 0) {
    #pragma unroll
    for (int r = 0; r < 4; ++r) {
      int grow = wsub * 16 + g * 4 + r;
      float m2 = shML[grow * 2], l2 = shML[grow * 2 + 1];
      float M = fmaxf(m[r], m2);
      float fa = __expf(m[r] - M), fb = __expf(m2 - M);
      float inv = 1.f / (l[r] * fa + l2 * fb);
      #pragma unroll
      for (int nt = 0; nt < 4; ++nt) {
        float val = (o[nt][r] * fa + shO[grow * 64 + nt * 16 + ln15] * fb) * inv;
        ctx[(size_t)(b * NS + q0 + grow) * ND + hh * NDK + nt * 16 + ln15] = f2bf(val);
      }
    }
  }
}

// ---------------- layernorm: 4 rows/block, shuffle-reduce, no barriers -------
__global__ __launch_bounds__(256) void k_ln(float* __restrict__ h,
                                            short* __restrict__ hb,
                                            const float* __restrict__ g_,
                                            const float* __restrict__ b_, int q_base) {
  int lane = threadIdx.x & 63, r4 = threadIdx.x >> 6;
  size_t row = (size_t)blockIdx.y * NS + q_base + blockIdx.x * 4 + r4;
  float4 v = ((const float4*)&h[row * ND])[lane];
  float s = v.x + v.y + v.z + v.w;
  #pragma unroll
  for (int off = 1; off < 64; off <<= 1) s += __shfl_xor(s, off, 64);
  float mu = s * (1.f / ND);
  float dx = v.x - mu, dy = v.y - mu, dz = v.z - mu, dw = v.w - mu;
  float q = dx * dx + dy * dy + dz * dz + dw * dw;
  #pragma unroll
  for (int off = 1; off < 64; off <<= 1) q += __shfl_xor(q, off, 64);
  float rr = rsqrtf(q * (1.f / ND) + 1e-5f);
  float4 gg = ((const float4*)g_)[lane];
  float4 bb = ((const float4*)b_)[lane];
  float4 o;
  o.x = dx * rr * gg.x + bb.x;
  o.y = dy * rr * gg.y + bb.y;
  o.z = dz * rr * gg.z + bb.z;
  o.w = dw * rr * gg.w + bb.w;
  ((float4*)&h[row * ND])[lane] = o;
  short4 ob; ob.x = f2bf(o.x); ob.y = f2bf(o.y); ob.z = f2bf(o.z); ob.w = f2bf(o.w);
  ((short4*)&hb[row * ND])[lane] = ob;
}

// ---------------- classifier head on last token ------------------------------
__global__ __launch_bounds__(128) void k_head(const float* __restrict__ h,
                                              const float* __restrict__ Wc1,
                                              const float* __restrict__ bc1,
                                              const float* __restrict__ Wc2,
                                              const float* __restrict__ bc2,
                                              float* __restrict__ out) {
  __shared__ float red[128];
  int j = threadIdx.x;
  for (int b = 0; b < NB; ++b) {
    const float* last = &h[(size_t)(b * NS + NS - 1) * ND];
    float acc = bc1[j];
    for (int d = 0; d < ND; ++d) acc = fmaf(last[d], Wc1[d * 128 + j], acc);
    acc = fmaxf(acc, 0.f);
    red[j] = acc * Wc2[j];
    __syncthreads();
    for (int off = 64; off > 0; off >>= 1) {
      if (j < off) red[j] += red[j + off];
      __syncthreads();
    }
    if (j == 0) out[b] = 1.f / (1.f + __expf(-(red[0] + bc2[0])));
    __syncthreads();
  }
}

}  // namespace

extern "C" void kernel_launch(void* const* d_in, const int* in_sizes, int n_in,
                              void* d_out, int out_size, void* d_ws, size_t ws_size,
                              hipStream_t stream) {
  const int* x = (const int*)d_in[0];
  const int* td = (const int*)d_in[1];
  const int* mask = (const int*)d_in[2];
  const float* ee = (const float*)d_in[3];
  const float* te = (const float*)d_in[4];
  const float* Wq = (const float*)d_in[5];
  const float* bq = (const float*)d_in[6];
  const float* Wk = (const float*)d_in[7];
  const float* bk = (const float*)d_in[8];
  const float* Wv = (const float*)d_in[9];
  const float* bv = (const float*)d_in[10];
  const float* tp = (const float*)d_in[11];
  const float* Wo = (const float*)d_in[12];
  const float* bo = (const float*)d_in[13];
  const float* lng = (const float*)d_in[14];
  const float* lnb = (const float*)d_in[15];
  const float* Wc1 = (const float*)d_in[16];
  const float* bc1 = (const float*)d_in[17];
  const float* Wc2 = (const float*)d_in[18];
  const float* bc2 = (const float*)d_in[19];
  float* out = (float*)d_out;

  char* ws = (char*)d_ws;
  const size_t M = (size_t)NB * NS;  // 8192
  float* h     = (float*)(ws);                       // 8 MB
  short* hb    = (short*)(ws + (8 << 20));           // 4 MB
  short* qkv   = (short*)(ws + (12 << 20));          // 12 MB  [M][768]
  short* ctx   = (short*)(ws + (24 << 20));          // 4 MB   [M][256]
  short* wqkvT = (short*)(ws + (28 << 20));          // 768 KB [2][768][256]
  short* woT   = (short*)(ws + (28 << 20) + 786432); // 256 KB [2][256][256]
  float* bqkv  = (float*)(ws + (29 << 20) + 262144); // 6 KB   [2][768]

  k_packw<<<dim3(4, 4, 8), 256, 0, stream>>>(Wq, Wk, Wv, Wo, wqkvT, woT);
  k_packb<<<2, 768, 0, stream>>>(bq, bk, bv, bqkv);
  k_embed<<<NB * NS / 4, 256, 0, stream>>>(x, td, ee, te, h, hb);

  for (int l = 0; l < NL; ++l) {
    const short* wqkvTl = wqkvT + (size_t)l * 768 * 256;
    const short* woTl = woT + (size_t)l * 65536;
    const float* bqkvl = bqkv + (size_t)l * 768;
    const float* bol = bo + (size_t)l * ND;
    const float* tpl = tp + (size_t)l * NT * NH;
    const float* lngl = lng + (size_t)l * ND;
    const float* lnbl = lnb + (size_t)l * ND;
    const bool last = (l == NL - 1);

    if (!last) {
      k_gemm<1><<<dim3(M / 64, 12), 256, 0, stream>>>(hb, wqkvTl, bqkvl, qkv, 768, 1, 0, 0);
    } else {
      k_gemm<1><<<dim3(M / 64, 8), 256, 0, stream>>>(hb, wqkvTl, bqkvl, qkv, 768, 1, 0, 256);
      k_gemm<1><<<dim3(NB, 4), 256, 0, stream>>>(hb, wqkvTl, bqkvl, qkv, 768, 32, 31, 0);
    }

    int qtiles = last ? 1 : NS / 64;
    int aq_base = last ? NS - 64 : 0;
    k_attn<<<dim3(qtiles, NH, NB), 512, 0, stream>>>(qkv, td, mask, tpl, ctx, aq_base);

    if (!last) {
      k_gemm<0><<<dim3(M / 64, 4), 256, 0, stream>>>(ctx, woTl, bol, h, 256, 1, 0, 0);
      k_ln<<<dim3(NS / 4, NB), 256, 0, stream>>>(h, hb, lngl, lnbl, 0);
    } else {
      k_gemm<0><<<dim3(NB, 4), 256, 0, stream>>>(ctx, woTl, bol, h, 256, 32, 31, 0);
      k_ln<<<dim3(1, NB), 256, 0, stream>>>(h, hb, lngl, lnbl, NS - 4);
    }
  }

  k_head<<<1, 128, 0, stream>>>(h, Wc1, bc1, Wc2, bc2, out);
}

// Round 5
// 189.666 us; speedup vs baseline: 6.1413x; 1.0061x over previous
//
#include <hip/hip_runtime.h>
#include <math.h>

namespace {

constexpr int NB = 4, NS = 2048, ND = 256, NH = 4, NDK = 64, NL = 2, NT = 1000;
constexpr float L2E = 1.44269504089f;       // log2(e)
constexpr float QSCALE = 0.125f * L2E;      // 1/sqrt(DK) * log2(e), folded into Wq/bq

typedef short bfx8 __attribute__((ext_vector_type(8)));
typedef float f32x4 __attribute__((ext_vector_type(4)));

static __device__ __forceinline__ short f2bf(float f) {
  union { float f; unsigned u; } v; v.f = f;
  unsigned u = v.u;
  unsigned r = (u + 0x7fffu + ((u >> 16) & 1u)) >> 16;   // RNE
  return (short)r;
}
static __device__ __forceinline__ float exp2_hw(float x) {
  float r;
  asm("v_exp_f32 %0, %1" : "=v"(r) : "v"(x));
  return r;
}
static __device__ __forceinline__ unsigned cvt_pk_bf16(float lo, float hi) {
  unsigned d;
  asm("v_cvt_pk_bf16_f32 %0, %1, %2" : "=v"(d) : "v"(lo), "v"(hi));
  return d;
}

// ---------------- weight pack: W[K][N] fp32 -> WT[N][K] bf16 -----------------
// Wq additionally pre-scaled by QSCALE (softmax scale + log2e folded in).
__global__ __launch_bounds__(256) void k_packw(const float* __restrict__ Wq,
                                               const float* __restrict__ Wk,
                                               const float* __restrict__ Wv,
                                               const float* __restrict__ Wo,
                                               short* __restrict__ wqkvT,
                                               short* __restrict__ woT) {
  __shared__ float t[64][65];
  int z = blockIdx.z, l = z >> 2, mat = z & 3;
  const float* src;
  short* dst;
  float scale = 1.f;
  if (mat == 0)      { src = Wq + (size_t)l * 65536; dst = wqkvT + (size_t)l * 768 * 256; scale = QSCALE; }
  else if (mat == 1) { src = Wk + (size_t)l * 65536; dst = wqkvT + (size_t)l * 768 * 256 + 256 * 256; }
  else if (mat == 2) { src = Wv + (size_t)l * 65536; dst = wqkvT + (size_t)l * 768 * 256 + 512 * 256; }
  else               { src = Wo + (size_t)l * 65536; dst = woT + (size_t)l * 65536; }
  int k0 = blockIdx.x * 64, n0 = blockIdx.y * 64;
  int c = threadIdx.x & 63, r4 = threadIdx.x >> 6;
  #pragma unroll
  for (int rr = 0; rr < 64; rr += 4) t[rr + r4][c] = src[(size_t)(k0 + rr + r4) * 256 + n0 + c];
  __syncthreads();
  #pragma unroll
  for (int rr = 0; rr < 64; rr += 4) {
    int n = rr + r4;
    dst[(size_t)(n0 + n) * 256 + k0 + c] = f2bf(t[c][n] * scale);
  }
}

__global__ __launch_bounds__(768) void k_packb(const float* __restrict__ bq,
                                               const float* __restrict__ bk,
                                               const float* __restrict__ bv,
                                               float* __restrict__ bqkv) {
  int l = blockIdx.x, c = threadIdx.x;
  float v;
  if (c < 256) v = bq[l * 256 + c] * QSCALE;
  else if (c < 512) v = bk[l * 256 + c - 256];
  else v = bv[l * 256 + c - 512];
  bqkv[l * 768 + c] = v;
}

// ---------------- embedding gather (float4, 4 rows/block) --------------------
__global__ __launch_bounds__(256) void k_embed(const int* __restrict__ x,
                                               const int* __restrict__ td,
                                               const float* __restrict__ ee,
                                               const float* __restrict__ te,
                                               float* __restrict__ h,
                                               short* __restrict__ hb) {
  int lane = threadIdx.x & 63, r4 = threadIdx.x >> 6;
  int row = blockIdx.x * 4 + r4;
  int xi = x[row];
  int tb = td[row];
  tb = tb < 0 ? 0 : (tb >= NT ? NT - 1 : tb);
  float4 e = ((const float4*)&ee[(size_t)xi * ND])[lane];
  float4 tv = ((const float4*)&te[(size_t)tb * ND])[lane];
  float4 v;
  v.x = e.x + tv.x; v.y = e.y + tv.y; v.z = e.z + tv.z; v.w = e.w + tv.w;
  ((float4*)&h[(size_t)row * ND])[lane] = v;
  short4 ob; ob.x = f2bf(v.x); ob.y = f2bf(v.y); ob.z = f2bf(v.z); ob.w = f2bf(v.w);
  ((short4*)&hb[(size_t)row * ND])[lane] = ob;
}

// ---------------- MFMA GEMM: C[M][N] = A[M][256] @ WT^T + bias ---------------
template <int OUT_BF16>
__global__ __launch_bounds__(256) void k_gemm(const short* __restrict__ A,
                                              const short* __restrict__ BT,
                                              const float* __restrict__ bias,
                                              void* __restrict__ C, int ldc,
                                              int mb_mul, int mb_add, int n_base) {
  constexpr int LP = 76;
  __shared__ short at[64][LP];
  __shared__ short bt[64][LP];
  int tid = threadIdx.x;
  int w = tid >> 6, lane = tid & 63, ln15 = lane & 15, g = lane >> 4;
  int m0 = (blockIdx.x * mb_mul + mb_add) * 64;
  int n0 = n_base + blockIdx.y * 64;
  int srow = tid >> 2, scol = (tid & 3) * 16;

  f32x4 acc[4];
  #pragma unroll
  for (int nt = 0; nt < 4; ++nt) acc[nt] = (f32x4){0.f, 0.f, 0.f, 0.f};

  bfx8 a0, a1, b0, b1;
  auto LOAD = [&](int kk0) {
    const short* as = &A[(size_t)(m0 + srow) * 256 + kk0 + scol];
    const short* bs = &BT[(size_t)(n0 + srow) * 256 + kk0 + scol];
    a0 = *(const bfx8*)as; a1 = *(const bfx8*)(as + 8);
    b0 = *(const bfx8*)bs; b1 = *(const bfx8*)(bs + 8);
  };
  LOAD(0);
  for (int kk0 = 0; kk0 < 256; kk0 += 64) {
    __syncthreads();
    *(bfx8*)&at[srow][scol] = a0; *(bfx8*)&at[srow][scol + 8] = a1;
    *(bfx8*)&bt[srow][scol] = b0; *(bfx8*)&bt[srow][scol + 8] = b1;
    if (kk0 + 64 < 256) LOAD(kk0 + 64);
    __syncthreads();
    #pragma unroll
    for (int ks = 0; ks < 2; ++ks) {
      bfx8 af = *(const bfx8*)&at[w * 16 + ln15][ks * 32 + g * 8];
      #pragma unroll
      for (int nt = 0; nt < 4; ++nt) {
        bfx8 bf = *(const bfx8*)&bt[nt * 16 + ln15][ks * 32 + g * 8];
        acc[nt] = __builtin_amdgcn_mfma_f32_16x16x32_bf16(af, bf, acc[nt], 0, 0, 0);
      }
    }
  }

  #pragma unroll
  for (int nt = 0; nt < 4; ++nt) {
    int col = n0 + nt * 16 + ln15;
    float bb = bias[col];
    #pragma unroll
    for (int r = 0; r < 4; ++r) {
      int row = m0 + w * 16 + g * 4 + r;
      float val = acc[nt][r] + bb;
      if (OUT_BF16) ((short*)C)[(size_t)row * ldc + col] = f2bf(val);
      else          ((float*)C)[(size_t)row * ldc + col] = val;
    }
  }
}

// ---------------- MFMA flash attention, swapped operands ---------------------
// 512 threads = 8 waves; wsub=w&3 owns 16 queries (as MFMA columns), half=w>>2
// owns half the KV range. QK^T: D=P^T[key][q] via mfma(K,Q); bias+mask ride in
// K-dim 64 (Q dim64=1). PV: O^T=V^T P^T via mfma(V^T, cvt_pk(P)) with V staged
// column-permuted so registers ARE the B-fragment. lsum = ones-row of V^T.
__global__ __launch_bounds__(512, 6) void k_attn(const short* __restrict__ qkv,
                                                 const int* __restrict__ td,
                                                 const int* __restrict__ mask,
                                                 const float* __restrict__ tp,
                                                 short* __restrict__ ctx, int q_base) {
  constexpr int LPK = 100;  // 50-dword row stride: conflict-free frag reads
  constexpr int LPV = 76;
  __shared__ short kt[2][64][LPK];   // K tile [key][dim 0..63, 64=bias, 65..95=0]
  __shared__ short vt[2][80][LPV];   // V^T [dim][permuted key]; row 64 = ones

  int tid = threadIdx.x;
  int w = tid >> 6, lane = tid & 63, ln15 = lane & 15, g = lane >> 4;
  int half = w >> 2, wsub = w & 3;
  int t = tid & 255;
  int b = blockIdx.z, hh = blockIdx.y;
  int q0 = q_base + blockIdx.x * 64;
  int qw0 = q0 + wsub * 16;

  // one-time static regions (ordered before first use by loop-top barrier)
  for (int idx = tid; idx < 2 * 64 * 35; idx += 512) {
    int h2 = idx / (64 * 35), rem = idx % (64 * 35);
    kt[h2][rem / 35][65 + rem % 35] = 0;
  }
  for (int idx = tid; idx < 2 * 16 * LPV; idx += 512) {
    int h2 = idx / (16 * LPV), rem = idx % (16 * LPV), j = rem / LPV, c = rem % LPV;
    vt[h2][64 + j][c] = (j == 0 && c < 64) ? (short)0x3F80 : (short)0;
  }

  // Q fragments (B-operand): lane holds query col ln15, dims g*8..g*8+7
  bfx8 aq[3];
  #pragma unroll
  for (int ks = 0; ks < 2; ++ks)
    aq[ks] = *(const bfx8*)&qkv[(size_t)(b * NS + qw0 + ln15) * 768 + hh * NDK + ks * 32 + g * 8];
  {
    bfx8 z = (bfx8){0, 0, 0, 0, 0, 0, 0, 0};
    if (g == 0) z[0] = (short)0x3F80;   // Q[dim 64] = 1.0
    aq[2] = z;
  }

  f32x4 o[5];
  #pragma unroll
  for (int dt = 0; dt < 5; ++dt) o[dt] = (f32x4){0.f, 0.f, 0.f, 0.f};
  float m = -1e30f;

  // staging geometry
  int srow = t >> 2, scg = (t & 3) * 16;
  bool needB = (t & 3) == 0;
  int vlane = t & 63, vw4 = (t >> 6) & 3;
  // permuted V column: key=16nt+4g'+r -> c=32(nt>>1)+8g'+4(nt&1)+r
  int pks = vlane >> 5, ptt = (vlane >> 4) & 1, pgg = (vlane >> 2) & 3, prr = vlane & 3;
  int vcol = pks * 32 + pgg * 8 + ptt * 4 + prr;

  bfx8 kr0, kr1, vr0, vr1;
  float br = 0.f;
  auto LOAD = [&](int it) {
    int k0 = (half * 16 + it) * 64;
    const short* ksrc = &qkv[(size_t)(b * NS + k0 + srow) * 768 + 256 + hh * NDK + scg];
    kr0 = *(const bfx8*)ksrc; kr1 = *(const bfx8*)(ksrc + 8);
    const short* vsrc = &qkv[(size_t)(b * NS + k0 + vlane) * 768 + 512 + hh * NDK + vw4 * 16];
    vr0 = *(const bfx8*)vsrc; vr1 = *(const bfx8*)(vsrc + 8);
    if (needB) {
      int key = k0 + srow;
      int tb = td[b * NS + key];
      tb = tb < 0 ? 0 : (tb >= NT ? NT - 1 : tb);
      br = mask[b * NS + key] ? tp[tb * NH + hh] * L2E : -1e9f;
    }
  };
  LOAD(0);

  for (int it = 0; it < 16; ++it) {
    __syncthreads();
    *(bfx8*)&kt[half][srow][scg] = kr0;
    *(bfx8*)&kt[half][srow][scg + 8] = kr1;
    if (needB) kt[half][srow][64] = f2bf(br);
    #pragma unroll
    for (int i = 0; i < 8; ++i) {
      vt[half][vw4 * 16 + i][vcol] = vr0[i];
      vt[half][vw4 * 16 + 8 + i][vcol] = vr1[i];
    }
    if (it + 1 < 16) LOAD(it + 1);
    __syncthreads();

    // QK^T swapped: c[nt][r] = score of key 16nt+4g+r for query ln15
    f32x4 c[4];
    #pragma unroll
    for (int nt = 0; nt < 4; ++nt) {
      c[nt] = (f32x4){0.f, 0.f, 0.f, 0.f};
      #pragma unroll
      for (int ks = 0; ks < 3; ++ks) {
        bfx8 kf = *(const bfx8*)&kt[half][nt * 16 + ln15][ks * 32 + g * 8];
        c[nt] = __builtin_amdgcn_mfma_f32_16x16x32_bf16(kf, aq[ks], c[nt], 0, 0, 0);
      }
    }

    // row max: in-lane 16 + cross-group (same query) 2 shuffles
    float rm = c[0][0];
    #pragma unroll
    for (int nt = 0; nt < 4; ++nt)
      #pragma unroll
      for (int r = 0; r < 4; ++r) rm = fmaxf(rm, c[nt][r]);
    rm = fmaxf(rm, __shfl_xor(rm, 16, 64));
    rm = fmaxf(rm, __shfl_xor(rm, 32, 64));

    // defer-max (log2 units): P bounded by 2^10
    if (__any(rm > m + 10.f)) {
      float nm = fmaxf(m, rm);
      float scl = exp2_hw(m - nm);
      m = nm;
      #pragma unroll
      for (int dt = 0; dt < 5; ++dt)
        #pragma unroll
        for (int r = 0; r < 4; ++r) o[dt][r] *= scl;
    }

    // P = exp2(score - m), packed straight into the PV B-fragment
    unsigned pb[2][4];
    #pragma unroll
    for (int nt = 0; nt < 4; ++nt) {
      float e0 = exp2_hw(c[nt][0] - m), e1 = exp2_hw(c[nt][1] - m);
      float e2 = exp2_hw(c[nt][2] - m), e3 = exp2_hw(c[nt][3] - m);
      pb[nt >> 1][(nt & 1) * 2]     = cvt_pk_bf16(e0, e1);
      pb[nt >> 1][(nt & 1) * 2 + 1] = cvt_pk_bf16(e2, e3);
    }

    // PV: O^T += V^T @ P^T  (dt=4 is the ones-row -> lsum)
    #pragma unroll
    for (int ks = 0; ks < 2; ++ks) {
      union { unsigned u[4]; bfx8 v; } pf;
      pf.u[0] = pb[ks][0]; pf.u[1] = pb[ks][1]; pf.u[2] = pb[ks][2]; pf.u[3] = pb[ks][3];
      #pragma unroll
      for (int dt = 0; dt < 5; ++dt) {
        bfx8 vf = *(const bfx8*)&vt[half][dt * 16 + ln15][ks * 32 + g * 8];
        o[dt] = __builtin_amdgcn_mfma_f32_16x16x32_bf16(vf, pf.v, o[dt], 0, 0, 0);
      }
    }
  }

  // ---- merge halves: lane holds query ln15, dims 16dt+4g+r ----
  float* shO = (float*)&kt[0][0][0];   // [64 q][68 stride] fp32 (17.4 KB)
  float* shML = (float*)&vt[0][0][0];  // [64 q][2]
  __syncthreads();
  int q = wsub * 16 + ln15;
  if (half == 1) {
    #pragma unroll
    for (int dt = 0; dt < 4; ++dt) {
      float4 st; st.x = o[dt][0]; st.y = o[dt][1]; st.z = o[dt][2]; st.w = o[dt][3];
      *(float4*)&shO[q * 68 + dt * 16 + g * 4] = st;
    }
    if (g == 0) { shML[q * 2] = m; shML[q * 2 + 1] = o[4][0]; }
  }
  __syncthreads();
  if (half == 0) {
    float l = __shfl(o[4][0], ln15, 64);   // lsum of query ln15 (from g==0 lane)
    float m2 = shML[q * 2], l2 = shML[q * 2 + 1];
    float M = fmaxf(m, m2);
    float fa = exp2_hw(m - M), fb = exp2_hw(m2 - M);
    float inv = 1.f / (l * fa + l2 * fb);
    fa *= inv; fb *= inv;
    #pragma unroll
    for (int dt = 0; dt < 4; ++dt) {
      float4 sh = *(const float4*)&shO[q * 68 + dt * 16 + g * 4];
      float v0 = o[dt][0] * fa + sh.x * fb;
      float v1 = o[dt][1] * fa + sh.y * fb;
      float v2 = o[dt][2] * fa + sh.z * fb;
      float v3 = o[dt][3] * fa + sh.w * fb;
      int2 pk; pk.x = (int)cvt_pk_bf16(v0, v1); pk.y = (int)cvt_pk_bf16(v2, v3);
      *(int2*)&ctx[(size_t)(b * NS + q0 + q) * ND + hh * NDK + dt * 16 + g * 4] = pk;
    }
  }
}

// ---------------- layernorm: 4 rows/block, shuffle-reduce, no barriers -------
__global__ __launch_bounds__(256) void k_ln(float* __restrict__ h,
                                            short* __restrict__ hb,
                                            const float* __restrict__ g_,
                                            const float* __restrict__ b_, int q_base) {
  int lane = threadIdx.x & 63, r4 = threadIdx.x >> 6;
  size_t row = (size_t)blockIdx.y * NS + q_base + blockIdx.x * 4 + r4;
  float4 v = ((const float4*)&h[row * ND])[lane];
  float s = v.x + v.y + v.z + v.w;
  #pragma unroll
  for (int off = 1; off < 64; off <<= 1) s += __shfl_xor(s, off, 64);
  float mu = s * (1.f / ND);
  float dx = v.x - mu, dy = v.y - mu, dz = v.z - mu, dw = v.w - mu;
  float q = dx * dx + dy * dy + dz * dz + dw * dw;
  #pragma unroll
  for (int off = 1; off < 64; off <<= 1) q += __shfl_xor(q, off, 64);
  float rr = rsqrtf(q * (1.f / ND) + 1e-5f);
  float4 gg = ((const float4*)g_)[lane];
  float4 bb = ((const float4*)b_)[lane];
  float4 o;
  o.x = dx * rr * gg.x + bb.x;
  o.y = dy * rr * gg.y + bb.y;
  o.z = dz * rr * gg.z + bb.z;
  o.w = dw * rr * gg.w + bb.w;
  ((float4*)&h[row * ND])[lane] = o;
  short4 ob; ob.x = f2bf(o.x); ob.y = f2bf(o.y); ob.z = f2bf(o.z); ob.w = f2bf(o.w);
  ((short4*)&hb[row * ND])[lane] = ob;
}

// ---------------- classifier head on last token ------------------------------
__global__ __launch_bounds__(128) void k_head(const float* __restrict__ h,
                                              const float* __restrict__ Wc1,
                                              const float* __restrict__ bc1,
                                              const float* __restrict__ Wc2,
                                              const float* __restrict__ bc2,
                                              float* __restrict__ out) {
  __shared__ float red[128];
  int j = threadIdx.x;
  for (int b = 0; b < NB; ++b) {
    const float* last = &h[(size_t)(b * NS + NS - 1) * ND];
    float acc = bc1[j];
    for (int d = 0; d < ND; ++d) acc = fmaf(last[d], Wc1[d * 128 + j], acc);
    acc = fmaxf(acc, 0.f);
    red[j] = acc * Wc2[j];
    __syncthreads();
    for (int off = 64; off > 0; off >>= 1) {
      if (j < off) red[j] += red[j + off];
      __syncthreads();
    }
    if (j == 0) out[b] = 1.f / (1.f + __expf(-(red[0] + bc2[0])));
    __syncthreads();
  }
}

}  // namespace

extern "C" void kernel_launch(void* const* d_in, const int* in_sizes, int n_in,
                              void* d_out, int out_size, void* d_ws, size_t ws_size,
                              hipStream_t stream) {
  const int* x = (const int*)d_in[0];
  const int* td = (const int*)d_in[1];
  const int* mask = (const int*)d_in[2];
  const float* ee = (const float*)d_in[3];
  const float* te = (const float*)d_in[4];
  const float* Wq = (const float*)d_in[5];
  const float* bq = (const float*)d_in[6];
  const float* Wk = (const float*)d_in[7];
  const float* bk = (const float*)d_in[8];
  const float* Wv = (const float*)d_in[9];
  const float* bv = (const float*)d_in[10];
  const float* tp = (const float*)d_in[11];
  const float* Wo = (const float*)d_in[12];
  const float* bo = (const float*)d_in[13];
  const float* lng = (const float*)d_in[14];
  const float* lnb = (const float*)d_in[15];
  const float* Wc1 = (const float*)d_in[16];
  const float* bc1 = (const float*)d_in[17];
  const float* Wc2 = (const float*)d_in[18];
  const float* bc2 = (const float*)d_in[19];
  float* out = (float*)d_out;

  char* ws = (char*)d_ws;
  const size_t M = (size_t)NB * NS;  // 8192
  float* h     = (float*)(ws);                       // 8 MB
  short* hb    = (short*)(ws + (8 << 20));           // 4 MB
  short* qkv   = (short*)(ws + (12 << 20));          // 12 MB  [M][768]
  short* ctx   = (short*)(ws + (24 << 20));          // 4 MB   [M][256]
  short* wqkvT = (short*)(ws + (28 << 20));          // 768 KB [2][768][256]
  short* woT   = (short*)(ws + (28 << 20) + 786432); // 256 KB [2][256][256]
  float* bqkv  = (float*)(ws + (29 << 20) + 262144); // 6 KB   [2][768]

  k_packw<<<dim3(4, 4, 8), 256, 0, stream>>>(Wq, Wk, Wv, Wo, wqkvT, woT);
  k_packb<<<2, 768, 0, stream>>>(bq, bk, bv, bqkv);
  k_embed<<<NB * NS / 4, 256, 0, stream>>>(x, td, ee, te, h, hb);

  for (int l = 0; l < NL; ++l) {
    const short* wqkvTl = wqkvT + (size_t)l * 768 * 256;
    const short* woTl = woT + (size_t)l * 65536;
    const float* bqkvl = bqkv + (size_t)l * 768;
    const float* bol = bo + (size_t)l * ND;
    const float* tpl = tp + (size_t)l * NT * NH;
    const float* lngl = lng + (size_t)l * ND;
    const float* lnbl = lnb + (size_t)l * ND;
    const bool last = (l == NL - 1);

    if (!last) {
      k_gemm<1><<<dim3(M / 64, 12), 256, 0, stream>>>(hb, wqkvTl, bqkvl, qkv, 768, 1, 0, 0);
    } else {
      k_gemm<1><<<dim3(M / 64, 8), 256, 0, stream>>>(hb, wqkvTl, bqkvl, qkv, 768, 1, 0, 256);
      k_gemm<1><<<dim3(NB, 4), 256, 0, stream>>>(hb, wqkvTl, bqkvl, qkv, 768, 32, 31, 0);
    }

    int qtiles = last ? 1 : NS / 64;
    int aq_base = last ? NS - 64 : 0;
    k_attn<<<dim3(qtiles, NH, NB), 512, 0, stream>>>(qkv, td, mask, tpl, ctx, aq_base);

    if (!last) {
      k_gemm<0><<<dim3(M / 64, 4), 256, 0, stream>>>(ctx, woTl, bol, h, 256, 1, 0, 0);
      k_ln<<<dim3(NS / 4, NB), 256, 0, stream>>>(h, hb, lngl, lnbl, 0);
    } else {
      k_gemm<0><<<dim3(NB, 4), 256, 0, stream>>>(ctx, woTl, bol, h, 256, 32, 31, 0);
      k_ln<<<dim3(1, NB), 256, 0, stream>>>(h, hb, lngl, lnbl, NS - 4);
    }
  }

  k_head<<<1, 128, 0, stream>>>(h, Wc1, bc1, Wc2, bc2, out);
}

// Round 6
// 139.867 us; speedup vs baseline: 8.3279x; 1.3560x over previous
//
#include <hip/hip_runtime.h>
#include <math.h>

namespace {

constexpr int NB = 4, NS = 2048, ND = 256, NH = 4, NDK = 64, NL = 2, NT = 1000;
constexpr float L2E = 1.44269504089f;       // log2(e)
constexpr float QSCALE = 0.125f * L2E;      // 1/sqrt(DK) * log2(e), folded into Wq/bq

typedef short bfx8 __attribute__((ext_vector_type(8)));
typedef float f32x4 __attribute__((ext_vector_type(4)));

static __device__ __forceinline__ short f2bf(float f) {
  union { float f; unsigned u; } v; v.f = f;
  unsigned u = v.u;
  unsigned r = (u + 0x7fffu + ((u >> 16) & 1u)) >> 16;   // RNE
  return (short)r;
}
static __device__ __forceinline__ float exp2_hw(float x) {
  float r;
  asm("v_exp_f32 %0, %1" : "=v"(r) : "v"(x));
  return r;
}
static __device__ __forceinline__ unsigned cvt_pk_bf16(float lo, float hi) {
  unsigned d;
  asm("v_cvt_pk_bf16_f32 %0, %1, %2" : "=v"(d) : "v"(lo), "v"(hi));
  return d;
}

// ---------------- weight pack: W[K][N] fp32 -> WT[N][K] bf16 -----------------
__global__ __launch_bounds__(256) void k_packw(const float* __restrict__ Wq,
                                               const float* __restrict__ Wk,
                                               const float* __restrict__ Wv,
                                               const float* __restrict__ Wo,
                                               short* __restrict__ wqkvT,
                                               short* __restrict__ woT) {
  __shared__ float t[64][65];
  int z = blockIdx.z, l = z >> 2, mat = z & 3;
  const float* src;
  short* dst;
  float scale = 1.f;
  if (mat == 0)      { src = Wq + (size_t)l * 65536; dst = wqkvT + (size_t)l * 768 * 256; scale = QSCALE; }
  else if (mat == 1) { src = Wk + (size_t)l * 65536; dst = wqkvT + (size_t)l * 768 * 256 + 256 * 256; }
  else if (mat == 2) { src = Wv + (size_t)l * 65536; dst = wqkvT + (size_t)l * 768 * 256 + 512 * 256; }
  else               { src = Wo + (size_t)l * 65536; dst = woT + (size_t)l * 65536; }
  int k0 = blockIdx.x * 64, n0 = blockIdx.y * 64;
  int c = threadIdx.x & 63, r4 = threadIdx.x >> 6;
  #pragma unroll
  for (int rr = 0; rr < 64; rr += 4) t[rr + r4][c] = src[(size_t)(k0 + rr + r4) * 256 + n0 + c];
  __syncthreads();
  #pragma unroll
  for (int rr = 0; rr < 64; rr += 4) {
    int n = rr + r4;
    dst[(size_t)(n0 + n) * 256 + k0 + c] = f2bf(t[c][n] * scale);
  }
}

__global__ __launch_bounds__(768) void k_packb(const float* __restrict__ bq,
                                               const float* __restrict__ bk,
                                               const float* __restrict__ bv,
                                               float* __restrict__ bqkv) {
  int l = blockIdx.x, c = threadIdx.x;
  float v;
  if (c < 256) v = bq[l * 256 + c] * QSCALE;
  else if (c < 512) v = bk[l * 256 + c - 256];
  else v = bv[l * 256 + c - 512];
  bqkv[l * 768 + c] = v;
}

// ---------------- embedding gather (float4, 4 rows/block) --------------------
__global__ __launch_bounds__(256) void k_embed(const int* __restrict__ x,
                                               const int* __restrict__ td,
                                               const float* __restrict__ ee,
                                               const float* __restrict__ te,
                                               float* __restrict__ h,
                                               short* __restrict__ hb) {
  int lane = threadIdx.x & 63, r4 = threadIdx.x >> 6;
  int row = blockIdx.x * 4 + r4;
  int xi = x[row];
  int tb = td[row];
  tb = tb < 0 ? 0 : (tb >= NT ? NT - 1 : tb);
  float4 e = ((const float4*)&ee[(size_t)xi * ND])[lane];
  float4 tv = ((const float4*)&te[(size_t)tb * ND])[lane];
  float4 v;
  v.x = e.x + tv.x; v.y = e.y + tv.y; v.z = e.z + tv.z; v.w = e.w + tv.w;
  ((float4*)&h[(size_t)row * ND])[lane] = v;
  short4 ob; ob.x = f2bf(v.x); ob.y = f2bf(v.y); ob.z = f2bf(v.z); ob.w = f2bf(v.w);
  ((short4*)&hb[(size_t)row * ND])[lane] = ob;
}

// ---------------- MFMA GEMM: 64x128 tile, BK=64, K=256 -----------------------
template <int OUT_BF16>
__global__ __launch_bounds__(256) void k_gemm(const short* __restrict__ A,
                                              const short* __restrict__ BT,
                                              const float* __restrict__ bias,
                                              void* __restrict__ C, int ldc,
                                              int mb_mul, int mb_add, int n_base) {
  constexpr int LP = 76;
  __shared__ short at[64][LP];
  __shared__ short bt[128][LP];
  int tid = threadIdx.x;
  int w = tid >> 6, lane = tid & 63, ln15 = lane & 15, g = lane >> 4;
  int m0 = (blockIdx.x * mb_mul + mb_add) * 64;
  int n0 = n_base + blockIdx.y * 128;
  int srow = tid >> 2, scol = (tid & 3) * 16;      // A staging: 64 rows x 64
  int brow = tid >> 1, bcol = (tid & 1) * 32;      // B staging: 128 rows x 64

  f32x4 acc[8];
  #pragma unroll
  for (int nt = 0; nt < 8; ++nt) acc[nt] = (f32x4){0.f, 0.f, 0.f, 0.f};

  bfx8 a0, a1, b0, b1, b2, b3;
  auto LOAD = [&](int kk0) {
    const short* as = &A[(size_t)(m0 + srow) * 256 + kk0 + scol];
    a0 = *(const bfx8*)as; a1 = *(const bfx8*)(as + 8);
    const short* bs = &BT[(size_t)(n0 + brow) * 256 + kk0 + bcol];
    b0 = *(const bfx8*)bs; b1 = *(const bfx8*)(bs + 8);
    b2 = *(const bfx8*)(bs + 16); b3 = *(const bfx8*)(bs + 24);
  };
  LOAD(0);
  for (int kk0 = 0; kk0 < 256; kk0 += 64) {
    __syncthreads();
    *(bfx8*)&at[srow][scol] = a0; *(bfx8*)&at[srow][scol + 8] = a1;
    *(bfx8*)&bt[brow][bcol] = b0; *(bfx8*)&bt[brow][bcol + 8] = b1;
    *(bfx8*)&bt[brow][bcol + 16] = b2; *(bfx8*)&bt[brow][bcol + 24] = b3;
    if (kk0 + 64 < 256) LOAD(kk0 + 64);
    __syncthreads();
    #pragma unroll
    for (int ks = 0; ks < 2; ++ks) {
      bfx8 af = *(const bfx8*)&at[w * 16 + ln15][ks * 32 + g * 8];
      #pragma unroll
      for (int nt = 0; nt < 8; ++nt) {
        bfx8 bf = *(const bfx8*)&bt[nt * 16 + ln15][ks * 32 + g * 8];
        acc[nt] = __builtin_amdgcn_mfma_f32_16x16x32_bf16(af, bf, acc[nt], 0, 0, 0);
      }
    }
  }

  #pragma unroll
  for (int nt = 0; nt < 8; ++nt) {
    int col = n0 + nt * 16 + ln15;
    float bb = bias[col];
    #pragma unroll
    for (int r = 0; r < 4; ++r) {
      int row = m0 + w * 16 + g * 4 + r;
      float val = acc[nt][r] + bb;
      if (OUT_BF16) ((short*)C)[(size_t)row * ldc + col] = f2bf(val);
      else          ((float*)C)[(size_t)row * ldc + col] = val;
    }
  }
}

// ---------------- MFMA flash attention, swapped operands + split-K -----------
// 512 threads = 8 waves; wsub owns 16 queries (MFMA cols), half owns half the
// block's key range. nchunk=1: full KV, write ctx. nchunk>1: flash-decode
// partials (M, L, unnormalized O) per chunk.
__global__ __launch_bounds__(512, 4) void k_attn(const short* __restrict__ qkv,
                                                 const int* __restrict__ td,
                                                 const int* __restrict__ mask,
                                                 const float* __restrict__ tp,
                                                 short* __restrict__ ctx,
                                                 float* __restrict__ partO,
                                                 float* __restrict__ partML,
                                                 int q_base, int nchunk) {
  constexpr int LPK = 100;
  constexpr int LPV = 76;
  __shared__ short kt[2][64][LPK];   // [key][dim 0..63, 64=bias, 65..99=0]
  __shared__ short vt[2][80][LPV];   // V^T [dim][permuted key]; row 64 = ones

  int tid = threadIdx.x;
  int w = tid >> 6, lane = tid & 63, ln15 = lane & 15, g = lane >> 4;
  int half = w >> 2, wsub = w & 3;
  int t = tid & 255;
  int b = blockIdx.z, hh = blockIdx.y;
  int qtile = blockIdx.x / nchunk;
  int chunk = blockIdx.x - qtile * nchunk;
  int niter = NS / (128 * nchunk);
  int kbase = chunk * (NS / nchunk);
  int q0 = q_base + qtile * 64;
  int qw0 = q0 + wsub * 16;

  // one-time static regions
  for (int idx = tid; idx < 2 * 64 * 35; idx += 512) {
    int h2 = idx / (64 * 35), rem = idx % (64 * 35);
    kt[h2][rem / 35][65 + rem % 35] = 0;
  }
  for (int idx = tid; idx < 2 * 16 * LPV; idx += 512) {
    int h2 = idx / (16 * LPV), rem = idx % (16 * LPV), j = rem / LPV, c = rem % LPV;
    vt[h2][64 + j][c] = (j == 0 && c < 64) ? (short)0x3F80 : (short)0;
  }

  // Q fragments (B-operand): lane holds query col ln15, dims g*8..g*8+7
  bfx8 aq[3];
  #pragma unroll
  for (int ks = 0; ks < 2; ++ks)
    aq[ks] = *(const bfx8*)&qkv[(size_t)(b * NS + qw0 + ln15) * 768 + hh * NDK + ks * 32 + g * 8];
  {
    bfx8 z = (bfx8){0, 0, 0, 0, 0, 0, 0, 0};
    if (g == 0) z[0] = (short)0x3F80;   // Q[dim 64] = 1.0
    aq[2] = z;
  }

  f32x4 o[5];
  #pragma unroll
  for (int dt = 0; dt < 5; ++dt) o[dt] = (f32x4){0.f, 0.f, 0.f, 0.f};
  float m = -1e30f;

  // staging geometry
  int srow = t >> 2, scg = (t & 3) * 16;
  bool needB = (t & 3) == 0;
  int vlane = t & 63, vw4 = (t >> 6) & 3;
  int pks = vlane >> 5, ptt = (vlane >> 4) & 1, pgg = (vlane >> 2) & 3, prr = vlane & 3;
  int vcol = pks * 32 + pgg * 8 + ptt * 4 + prr;

  auto loadset = [&](int it, bfx8& KR0, bfx8& KR1, bfx8& VR0, bfx8& VR1, float& BR) {
    int k0 = kbase + (half * niter + it) * 64;
    const short* ksrc = &qkv[(size_t)(b * NS + k0 + srow) * 768 + 256 + hh * NDK + scg];
    KR0 = *(const bfx8*)ksrc; KR1 = *(const bfx8*)(ksrc + 8);
    const short* vsrc = &qkv[(size_t)(b * NS + k0 + vlane) * 768 + 512 + hh * NDK + vw4 * 16];
    VR0 = *(const bfx8*)vsrc; VR1 = *(const bfx8*)(vsrc + 8);
    if (needB) {
      int key = k0 + srow;
      int tb = td[b * NS + key];
      tb = tb < 0 ? 0 : (tb >= NT ? NT - 1 : tb);
      BR = mask[b * NS + key] ? tp[tb * NH + hh] * L2E : -1e9f;
    }
  };

  auto compute = [&]() {
    f32x4 c[4];
    #pragma unroll
    for (int nt = 0; nt < 4; ++nt) {
      c[nt] = (f32x4){0.f, 0.f, 0.f, 0.f};
      #pragma unroll
      for (int ks = 0; ks < 3; ++ks) {
        bfx8 kf = *(const bfx8*)&kt[half][nt * 16 + ln15][ks * 32 + g * 8];
        c[nt] = __builtin_amdgcn_mfma_f32_16x16x32_bf16(kf, aq[ks], c[nt], 0, 0, 0);
      }
    }
    float rm = c[0][0];
    #pragma unroll
    for (int nt = 0; nt < 4; ++nt)
      #pragma unroll
      for (int r = 0; r < 4; ++r) rm = fmaxf(rm, c[nt][r]);
    rm = fmaxf(rm, __shfl_xor(rm, 16, 64));
    rm = fmaxf(rm, __shfl_xor(rm, 32, 64));
    if (__any(rm > m + 10.f)) {
      float nm = fmaxf(m, rm);
      float scl = exp2_hw(m - nm);
      m = nm;
      #pragma unroll
      for (int dt = 0; dt < 5; ++dt)
        #pragma unroll
        for (int r = 0; r < 4; ++r) o[dt][r] *= scl;
    }
    unsigned pb[2][4];
    #pragma unroll
    for (int nt = 0; nt < 4; ++nt) {
      float e0 = exp2_hw(c[nt][0] - m), e1 = exp2_hw(c[nt][1] - m);
      float e2 = exp2_hw(c[nt][2] - m), e3 = exp2_hw(c[nt][3] - m);
      pb[nt >> 1][(nt & 1) * 2]     = cvt_pk_bf16(e0, e1);
      pb[nt >> 1][(nt & 1) * 2 + 1] = cvt_pk_bf16(e2, e3);
    }
    #pragma unroll
    for (int ks = 0; ks < 2; ++ks) {
      union { unsigned u[4]; bfx8 v; } pf;
      pf.u[0] = pb[ks][0]; pf.u[1] = pb[ks][1]; pf.u[2] = pb[ks][2]; pf.u[3] = pb[ks][3];
      #pragma unroll
      for (int dt = 0; dt < 5; ++dt) {
        bfx8 vf = *(const bfx8*)&vt[half][dt * 16 + ln15][ks * 32 + g * 8];
        o[dt] = __builtin_amdgcn_mfma_f32_16x16x32_bf16(vf, pf.v, o[dt], 0, 0, 0);
      }
    }
  };

  auto body = [&](bfx8& KR0, bfx8& KR1, bfx8& VR0, bfx8& VR1, float& BR,
                  int pf_it, bool do_pf) {
    __syncthreads();
    *(bfx8*)&kt[half][srow][scg] = KR0;
    *(bfx8*)&kt[half][srow][scg + 8] = KR1;
    if (needB) kt[half][srow][64] = f2bf(BR);
    #pragma unroll
    for (int i = 0; i < 8; ++i) {
      vt[half][vw4 * 16 + i][vcol] = VR0[i];
      vt[half][vw4 * 16 + 8 + i][vcol] = VR1[i];
    }
    if (do_pf) loadset(pf_it, KR0, KR1, VR0, VR1, BR);
    __syncthreads();
    compute();
  };

  bfx8 krA0, krA1, vrA0, vrA1; float brA = 0.f;
  bfx8 krB0, krB1, vrB0, vrB1; float brB = 0.f;
  loadset(0, krA0, krA1, vrA0, vrA1, brA);
  if (niter > 1) loadset(1, krB0, krB1, vrB0, vrB1, brB);

  for (int it = 0; it < niter; it += 2) {
    body(krA0, krA1, vrA0, vrA1, brA, it + 2, it + 2 < niter);
    if (it + 1 < niter)
      body(krB0, krB1, vrB0, vrB1, brB, it + 3, it + 3 < niter);
  }

  // ---- merge halves (lane holds query ln15, dims 16dt+4g+r) ----
  float* shO = (float*)&kt[0][0][0];   // [64 q][68 stride] fp32
  float* shML = (float*)&vt[0][0][0];  // [64 q][2]
  __syncthreads();
  int q = wsub * 16 + ln15;
  if (half == 1) {
    #pragma unroll
    for (int dt = 0; dt < 4; ++dt) {
      float4 st; st.x = o[dt][0]; st.y = o[dt][1]; st.z = o[dt][2]; st.w = o[dt][3];
      *(float4*)&shO[q * 68 + dt * 16 + g * 4] = st;
    }
    if (g == 0) { shML[q * 2] = m; shML[q * 2 + 1] = o[4][0]; }
  }
  __syncthreads();
  if (half == 0) {
    float l = __shfl(o[4][0], ln15, 64);
    float m2 = shML[q * 2], l2 = shML[q * 2 + 1];
    float M = fmaxf(m, m2);
    float fa = exp2_hw(m - M), fb = exp2_hw(m2 - M);
    if (nchunk == 1) {
      float inv = 1.f / (l * fa + l2 * fb);
      fa *= inv; fb *= inv;
      #pragma unroll
      for (int dt = 0; dt < 4; ++dt) {
        float4 sh = *(const float4*)&shO[q * 68 + dt * 16 + g * 4];
        float v0 = o[dt][0] * fa + sh.x * fb;
        float v1 = o[dt][1] * fa + sh.y * fb;
        float v2 = o[dt][2] * fa + sh.z * fb;
        float v3 = o[dt][3] * fa + sh.w * fb;
        int2 pk; pk.x = (int)cvt_pk_bf16(v0, v1); pk.y = (int)cvt_pk_bf16(v2, v3);
        *(int2*)&ctx[(size_t)(b * NS + q0 + q) * ND + hh * NDK + dt * 16 + g * 4] = pk;
      }
    } else {
      float L = l * fa + l2 * fb;
      size_t pidx = (size_t)(chunk * NB + b) * NH + hh;
      #pragma unroll
      for (int dt = 0; dt < 4; ++dt) {
        float4 sh = *(const float4*)&shO[q * 68 + dt * 16 + g * 4];
        float4 st;
        st.x = o[dt][0] * fa + sh.x * fb;
        st.y = o[dt][1] * fa + sh.y * fb;
        st.z = o[dt][2] * fa + sh.z * fb;
        st.w = o[dt][3] * fa + sh.w * fb;
        *(float4*)&partO[pidx * 4096 + q * 64 + dt * 16 + g * 4] = st;
      }
      if (g == 0) { partML[pidx * 128 + q * 2] = M; partML[pidx * 128 + q * 2 + 1] = L; }
    }
  }
}

// ---------------- flash-decode merge: combine nchunk partials ----------------
__global__ __launch_bounds__(256) void k_amerge(const float* __restrict__ partO,
                                                const float* __restrict__ partML,
                                                short* __restrict__ ctx,
                                                int q_base, int nchunk) {
  int b = blockIdx.x, hh = blockIdx.y;
  int q = threadIdx.x >> 2, d0 = (threadIdx.x & 3) * 16;
  float M = -1e30f;
  for (int c = 0; c < nchunk; ++c)
    M = fmaxf(M, partML[((size_t)(c * NB + b) * NH + hh) * 128 + q * 2]);
  float L = 0.f;
  float acc[16];
  #pragma unroll
  for (int i = 0; i < 16; ++i) acc[i] = 0.f;
  for (int c = 0; c < nchunk; ++c) {
    size_t pidx = (size_t)(c * NB + b) * NH + hh;
    float mc = partML[pidx * 128 + q * 2];
    float lc = partML[pidx * 128 + q * 2 + 1];
    float s = exp2_hw(mc - M);
    L += lc * s;
    const float4* op = (const float4*)&partO[pidx * 4096 + q * 64 + d0];
    #pragma unroll
    for (int i = 0; i < 4; ++i) {
      float4 v = op[i];
      acc[i * 4]     += v.x * s;
      acc[i * 4 + 1] += v.y * s;
      acc[i * 4 + 2] += v.z * s;
      acc[i * 4 + 3] += v.w * s;
    }
  }
  float inv = 1.f / L;
  short res[16];
  #pragma unroll
  for (int i = 0; i < 16; ++i) res[i] = f2bf(acc[i] * inv);
  int4 pk = *(const int4*)res;
  *(int4*)&ctx[(size_t)(b * NS + q_base + q) * ND + hh * NDK + d0] = pk;
}

// ---------------- layernorm: 4 rows/block, shuffle-reduce --------------------
__global__ __launch_bounds__(256) void k_ln(float* __restrict__ h,
                                            short* __restrict__ hb,
                                            const float* __restrict__ g_,
                                            const float* __restrict__ b_, int q_base) {
  int lane = threadIdx.x & 63, r4 = threadIdx.x >> 6;
  size_t row = (size_t)blockIdx.y * NS + q_base + blockIdx.x * 4 + r4;
  float4 v = ((const float4*)&h[row * ND])[lane];
  float s = v.x + v.y + v.z + v.w;
  #pragma unroll
  for (int off = 1; off < 64; off <<= 1) s += __shfl_xor(s, off, 64);
  float mu = s * (1.f / ND);
  float dx = v.x - mu, dy = v.y - mu, dz = v.z - mu, dw = v.w - mu;
  float q = dx * dx + dy * dy + dz * dz + dw * dw;
  #pragma unroll
  for (int off = 1; off < 64; off <<= 1) q += __shfl_xor(q, off, 64);
  float rr = rsqrtf(q * (1.f / ND) + 1e-5f);
  float4 gg = ((const float4*)g_)[lane];
  float4 bb = ((const float4*)b_)[lane];
  float4 o;
  o.x = dx * rr * gg.x + bb.x;
  o.y = dy * rr * gg.y + bb.y;
  o.z = dz * rr * gg.z + bb.z;
  o.w = dw * rr * gg.w + bb.w;
  ((float4*)&h[row * ND])[lane] = o;
  short4 ob; ob.x = f2bf(o.x); ob.y = f2bf(o.y); ob.z = f2bf(o.z); ob.w = f2bf(o.w);
  ((short4*)&hb[row * ND])[lane] = ob;
}

// ---------------- classifier head on last token ------------------------------
__global__ __launch_bounds__(128) void k_head(const float* __restrict__ h,
                                              const float* __restrict__ Wc1,
                                              const float* __restrict__ bc1,
                                              const float* __restrict__ Wc2,
                                              const float* __restrict__ bc2,
                                              float* __restrict__ out) {
  __shared__ float red[128];
  int j = threadIdx.x;
  int b = blockIdx.x;
  const float* last = &h[(size_t)(b * NS + NS - 1) * ND];
  float acc = bc1[j];
  for (int d = 0; d < ND; ++d) acc = fmaf(last[d], Wc1[d * 128 + j], acc);
  acc = fmaxf(acc, 0.f);
  red[j] = acc * Wc2[j];
  __syncthreads();
  for (int off = 64; off > 0; off >>= 1) {
    if (j < off) red[j] += red[j + off];
    __syncthreads();
  }
  if (j == 0) out[b] = 1.f / (1.f + __expf(-(red[0] + bc2[0])));
}

}  // namespace

extern "C" void kernel_launch(void* const* d_in, const int* in_sizes, int n_in,
                              void* d_out, int out_size, void* d_ws, size_t ws_size,
                              hipStream_t stream) {
  const int* x = (const int*)d_in[0];
  const int* td = (const int*)d_in[1];
  const int* mask = (const int*)d_in[2];
  const float* ee = (const float*)d_in[3];
  const float* te = (const float*)d_in[4];
  const float* Wq = (const float*)d_in[5];
  const float* bq = (const float*)d_in[6];
  const float* Wk = (const float*)d_in[7];
  const float* bk = (const float*)d_in[8];
  const float* Wv = (const float*)d_in[9];
  const float* bv = (const float*)d_in[10];
  const float* tp = (const float*)d_in[11];
  const float* Wo = (const float*)d_in[12];
  const float* bo = (const float*)d_in[13];
  const float* lng = (const float*)d_in[14];
  const float* lnb = (const float*)d_in[15];
  const float* Wc1 = (const float*)d_in[16];
  const float* bc1 = (const float*)d_in[17];
  const float* Wc2 = (const float*)d_in[18];
  const float* bc2 = (const float*)d_in[19];
  float* out = (float*)d_out;

  char* ws = (char*)d_ws;
  const size_t M = (size_t)NB * NS;  // 8192
  float* h      = (float*)(ws);                       // 8 MB
  short* hb     = (short*)(ws + (8 << 20));           // 4 MB
  short* qkv    = (short*)(ws + (12 << 20));          // 12 MB  [M][768]
  short* ctx    = (short*)(ws + (24 << 20));          // 4 MB   [M][256]
  short* wqkvT  = (short*)(ws + (28 << 20));          // 768 KB
  short* woT    = (short*)(ws + (28 << 20) + 786432); // 256 KB
  float* bqkv   = (float*)(ws + (29 << 20) + 262144); // 6 KB
  float* partO  = (float*)(ws + (30 << 20));          // 4 MB   [16 chunks][16 bh][64q][64d]
  float* partML = (float*)(ws + (34 << 20) + (256 << 10)); // 128 KB

  k_packw<<<dim3(4, 4, 8), 256, 0, stream>>>(Wq, Wk, Wv, Wo, wqkvT, woT);
  k_packb<<<2, 768, 0, stream>>>(bq, bk, bv, bqkv);
  k_embed<<<NB * NS / 4, 256, 0, stream>>>(x, td, ee, te, h, hb);

  for (int l = 0; l < NL; ++l) {
    const short* wqkvTl = wqkvT + (size_t)l * 768 * 256;
    const short* woTl = woT + (size_t)l * 65536;
    const float* bqkvl = bqkv + (size_t)l * 768;
    const float* bol = bo + (size_t)l * ND;
    const float* tpl = tp + (size_t)l * NT * NH;
    const float* lngl = lng + (size_t)l * ND;
    const float* lnbl = lnb + (size_t)l * ND;
    const bool last = (l == NL - 1);

    if (!last) {
      k_gemm<1><<<dim3(M / 64, 6), 256, 0, stream>>>(hb, wqkvTl, bqkvl, qkv, 768, 1, 0, 0);
    } else {
      k_gemm<1><<<dim3(M / 64, 4), 256, 0, stream>>>(hb, wqkvTl, bqkvl, qkv, 768, 1, 0, 256);
      k_gemm<1><<<dim3(NB, 2), 256, 0, stream>>>(hb, wqkvTl, bqkvl, qkv, 768, 32, 31, 0);
    }

    if (!last) {
      k_attn<<<dim3(NS / 64, NH, NB), 512, 0, stream>>>(qkv, td, mask, tpl, ctx,
                                                        nullptr, nullptr, 0, 1);
      k_gemm<0><<<dim3(M / 64, 2), 256, 0, stream>>>(ctx, woTl, bol, h, 256, 1, 0, 0);
      k_ln<<<dim3(NS / 4, NB), 256, 0, stream>>>(h, hb, lngl, lnbl, 0);
    } else {
      k_attn<<<dim3(16, NH, NB), 512, 0, stream>>>(qkv, td, mask, tpl, ctx,
                                                   partO, partML, NS - 64, 16);
      k_amerge<<<dim3(NB, NH), 256, 0, stream>>>(partO, partML, ctx, NS - 64, 16);
      k_gemm<0><<<dim3(NB, 2), 256, 0, stream>>>(ctx, woTl, bol, h, 256, 32, 31, 0);
      k_ln<<<dim3(1, NB), 256, 0, stream>>>(h, hb, lngl, lnbl, NS - 4);
    }
  }

  k_head<<<NB, 128, 0, stream>>>(h, Wc1, bc1, Wc2, bc2, out);
}